// Round 2
// baseline (12506.954 us; speedup 1.0000x reference)
//
#include <hip/hip_runtime.h>
#include <cstdint>
#include <cstddef>

#define EMB 300
#define EMB2 600
#define NLAYER 5

static inline int cdiv(int a, int b) { return (a + b - 1) / b; }

// ---------------- zero fill (replaces hipMemsetAsync; capture-safe) ----------------
__global__ __launch_bounds__(256) void zero_kernel(float* __restrict__ p, size_t n)
{
    size_t i = (size_t)blockIdx.x * blockDim.x + threadIdx.x;
    size_t stride = (size_t)gridDim.x * blockDim.x;
    for (; i < n; i += stride) p[i] = 0.f;
}
static inline void launch_zero(float* p, size_t n, hipStream_t s)
{
    int g = (int)((n + 255) / 256);
    if (g > 2048) g = 2048;
    zero_kernel<<<g, 256, 0, s>>>(p, n);
}

// ---------------- embed: h = atom1[x0] + atom2[x1] ----------------
__global__ __launch_bounds__(256) void embed_kernel(
    const int* __restrict__ x, const float* __restrict__ a1,
    const float* __restrict__ a2, float* __restrict__ h, int N)
{
    int idx = blockIdx.x * blockDim.x + threadIdx.x;
    if (idx >= N * EMB) return;
    int row = idx / EMB, col = idx % EMB;
    h[idx] = a1[x[2 * row] * EMB + col] + a2[x[2 * row + 1] * EMB + col];
}

// ---------------- agg = h + selfloop_const ----------------
__global__ __launch_bounds__(256) void agg_init_kernel(
    const float* __restrict__ h, const float* __restrict__ e1,
    const float* __restrict__ e2, float* __restrict__ agg, int N)
{
    int idx = blockIdx.x * blockDim.x + threadIdx.x;
    if (idx >= N * EMB) return;
    int col = idx % EMB;
    agg[idx] = h[idx] + e1[4 * EMB + col] + e2[col];
}

// ---------------- GIN edge scatter: agg[dst] += h[src] + eemb ----------------
__global__ __launch_bounds__(256) void gin_scatter_kernel(
    const float* __restrict__ h, const int* __restrict__ src,
    const int* __restrict__ dst, const int* __restrict__ ea,
    const float* __restrict__ e1, const float* __restrict__ e2,
    float* __restrict__ agg, int E)
{
    int wv = (blockIdx.x * blockDim.x + threadIdx.x) >> 6;
    int lane = threadIdx.x & 63;
    if (wv >= E) return;
    int s = src[wv], d = dst[wv];
    int a0 = ea[2 * wv], a1 = ea[2 * wv + 1];
    const float* hs = h + (size_t)s * EMB;
    const float* t1 = e1 + (size_t)a0 * EMB;
    const float* t2 = e2 + (size_t)a1 * EMB;
    float* ad = agg + (size_t)d * EMB;
    for (int c = lane; c < EMB; c += 64)
        atomicAdd(&ad[c], hs[c] + t1[c] + t2[c]);
}

// ---------------- GEMM: C[M,Nc] = act(A[M,K] @ W[K,Nc] + bias) ----------------
#define TS 64
#define BKK 16
__global__ __launch_bounds__(256) void gemm_bias_act(
    const float* __restrict__ A, const float* __restrict__ W,
    const float* __restrict__ bias, float* __restrict__ C,
    int M, int K, int Nc, int relu_flag)
{
    __shared__ float As[BKK][TS + 4];
    __shared__ float Bs[BKK][TS + 4];
    const int tid = threadIdx.x;
    const int tx = tid & 15, ty = tid >> 4;
    const int row0 = blockIdx.y * TS, col0 = blockIdx.x * TS;
    const int lka = tid & 15, lra = tid >> 4;   // A tile load: k, row
    const int lnb = tid & 63, lkb = tid >> 6;   // B tile load: n, k
    float acc[4][4] = {};
    for (int k0 = 0; k0 < K; k0 += BKK) {
        #pragma unroll
        for (int i = 0; i < 4; ++i) {
            int rr = lra + 16 * i;
            int gr = row0 + rr, gk = k0 + lka;
            As[lka][rr] = (gr < M && gk < K) ? A[(size_t)gr * K + gk] : 0.f;
        }
        #pragma unroll
        for (int i = 0; i < 4; ++i) {
            int kk = lkb + 4 * i;
            int gk = k0 + kk, gn = col0 + lnb;
            Bs[kk][lnb] = (gk < K && gn < Nc) ? W[(size_t)gk * Nc + gn] : 0.f;
        }
        __syncthreads();
        #pragma unroll
        for (int kk = 0; kk < BKK; ++kk) {
            float a[4], b[4];
            #pragma unroll
            for (int i = 0; i < 4; ++i) a[i] = As[kk][ty * 4 + i];
            #pragma unroll
            for (int j = 0; j < 4; ++j) b[j] = Bs[kk][tx * 4 + j];
            #pragma unroll
            for (int i = 0; i < 4; ++i)
                #pragma unroll
                for (int j = 0; j < 4; ++j)
                    acc[i][j] = fmaf(a[i], b[j], acc[i][j]);
        }
        __syncthreads();
    }
    #pragma unroll
    for (int i = 0; i < 4; ++i) {
        int gr = row0 + ty * 4 + i;
        if (gr >= M) continue;
        #pragma unroll
        for (int j = 0; j < 4; ++j) {
            int gn = col0 + tx * 4 + j;
            if (gn >= Nc) continue;
            float v = acc[i][j] + bias[gn];
            if (relu_flag) v = fmaxf(v, 0.f);
            C[(size_t)gr * Nc + gn] = v;
        }
    }
}

// ---------------- BN column stats (sum, sumsq) ----------------
__global__ __launch_bounds__(320) void bn_stats_kernel(
    const float* __restrict__ H, float* __restrict__ stats, int M, int rpb)
{
    int col = threadIdx.x;
    if (col >= EMB) return;
    int r0 = blockIdx.x * rpb;
    int r1 = min(M, r0 + rpb);
    float s = 0.f, s2 = 0.f;
    for (int r = r0; r < r1; ++r) {
        float v = H[(size_t)r * EMB + col];
        s += v;
        s2 = fmaf(v, v, s2);
    }
    atomicAdd(&stats[col], s);
    atomicAdd(&stats[EMB + col], s2);
}

// ---------------- BN apply (+ optional relu) ----------------
__global__ __launch_bounds__(256) void bn_apply_kernel(
    const float* __restrict__ h2, const float* __restrict__ stats,
    const float* __restrict__ g, const float* __restrict__ b,
    float* __restrict__ hout, int N, int relu_flag, float invN)
{
    int idx = blockIdx.x * blockDim.x + threadIdx.x;
    if (idx >= N * EMB) return;
    int col = idx % EMB;
    float mu = stats[col] * invN;
    float var = fmaf(-mu, mu, stats[EMB + col] * invN);
    float v = (h2[idx] - mu) * rsqrtf(var + 1e-5f) * g[col] + b[col];
    if (relu_flag) v = fmaxf(v, 0.f);
    hout[idx] = v;
}

// ---------------- fragment mean-pool scatter ----------------
__global__ __launch_bounds__(256) void pool_scatter_kernel(
    const float* __restrict__ h, const int* __restrict__ fb,
    float* __restrict__ pooled, float* __restrict__ cnt, int N)
{
    int wv = (blockIdx.x * blockDim.x + threadIdx.x) >> 6;
    int lane = threadIdx.x & 63;
    if (wv >= N) return;
    int p = fb[wv];
    const float* hr = h + (size_t)wv * EMB;
    float* pr = pooled + (size_t)p * EMB;
    for (int c = lane; c < EMB; c += 64) atomicAdd(&pr[c], hr[c]);
    if (lane == 0) atomicAdd(&cnt[p], 1.f);
}

__global__ __launch_bounds__(256) void pool_div_kernel(
    float* __restrict__ pooled, const float* __restrict__ cnt, int P)
{
    int idx = blockIdx.x * blockDim.x + threadIdx.x;
    if (idx >= P * EMB) return;
    pooled[idx] /= fmaxf(cnt[idx / EMB], 1.f);
}

// ---------------- row L2 normalize ----------------
__global__ __launch_bounds__(256) void normalize_rows_kernel(
    const float* __restrict__ X, float* __restrict__ Y, int M)
{
    int wv = (blockIdx.x * blockDim.x + threadIdx.x) >> 6;
    int lane = threadIdx.x & 63;
    if (wv >= M) return;
    const float* x = X + (size_t)wv * EMB;
    float ss = 0.f;
    for (int c = lane; c < EMB; c += 64) { float v = x[c]; ss = fmaf(v, v, ss); }
    #pragma unroll
    for (int o = 32; o > 0; o >>= 1) ss += __shfl_xor(ss, o, 64);
    float inv = 1.f / fmaxf(sqrtf(ss), 1e-12f);
    float* y = Y + (size_t)wv * EMB;
    for (int c = lane; c < EMB; c += 64) y[c] = x[c] * inv;
}

// ---------------- GCN degree ----------------
__global__ __launch_bounds__(256) void deg_kernel(
    const int* __restrict__ fei, float* __restrict__ deg, int FE)
{
    int i = blockIdx.x * blockDim.x + threadIdx.x;
    if (i < 2 * FE) atomicAdd(&deg[fei[i]], 1.f);
}

// ---------------- GCN edge scatter ----------------
__global__ __launch_bounds__(256) void gcn_scatter_kernel(
    const float* __restrict__ xw, const int* __restrict__ fei,
    const int* __restrict__ dea, const float* __restrict__ e1,
    const float* __restrict__ e2, const float* __restrict__ deg,
    float* __restrict__ pred, int FE)
{
    int i = (blockIdx.x * blockDim.x + threadIdx.x) >> 6;
    int lane = threadIdx.x & 63;
    if (i >= 2 * FE) return;
    int u = fei[i];
    int v = (i < FE) ? fei[i + FE] : fei[i - FE];
    int er = (i < FE) ? i : i - FE;
    int a0 = dea[2 * er], a1 = dea[2 * er + 1];
    float du = deg[u], dv = deg[v];
    float su = du > 0.f ? rsqrtf(fmaxf(du, 1.f)) : 0.f;
    float sv = dv > 0.f ? rsqrtf(fmaxf(dv, 1.f)) : 0.f;
    float nr = su * sv;
    const float* xu = xw + (size_t)u * EMB;
    const float* t1 = e1 + (size_t)a0 * EMB;
    const float* t2 = e2 + (size_t)a1 * EMB;
    float* pv = pred + (size_t)v * EMB;
    for (int c = lane; c < EMB; c += 64)
        atomicAdd(&pv[c], nr * (xu[c] + t1[c] + t2[c]));
}

// ---------------- classifier: out[q] = sum(max(f0,f1or2) * w) + b ----------------
__global__ __launch_bounds__(256) void classifier_kernel(
    const float* __restrict__ f0, const float* __restrict__ f1,
    const float* __restrict__ w, const float* __restrict__ b,
    float* __restrict__ out, int P)
{
    int q = (blockIdx.x * blockDim.x + threadIdx.x) >> 6;
    int lane = threadIdx.x & 63;
    if (q >= 2 * P) return;
    int i = (q < P) ? q : q - P;
    int j = (q < P) ? i : (i == 0 ? P - 1 : i - 1);
    const float* a = f0 + (size_t)i * EMB;
    const float* c = f1 + (size_t)j * EMB;
    float s = 0.f;
    for (int k = lane; k < EMB; k += 64) s = fmaf(fmaxf(a[k], c[k]), w[k], s);
    #pragma unroll
    for (int o = 32; o > 0; o >>= 1) s += __shfl_xor(s, o, 64);
    if (lane == 0) out[q] = s + b[0];
}

extern "C" void kernel_launch(void* const* d_in, const int* in_sizes, int n_in,
                              void* d_out, int out_size, void* d_ws, size_t ws_size,
                              hipStream_t stream)
{
    const int*   x     = (const int*)d_in[0];
    const int*   ei    = (const int*)d_in[1];
    const int*   ea    = (const int*)d_in[2];
    const int*   fb    = (const int*)d_in[3];
    const int*   fei   = (const int*)d_in[4];
    const int*   dea   = (const int*)d_in[5];
    const float* atom1 = (const float*)d_in[7];
    const float* atom2 = (const float*)d_in[8];
    const float* ge1   = (const float*)d_in[9];    // [L,6,EMB]
    const float* ge2   = (const float*)d_in[10];   // [L,3,EMB]
    const float* w1    = (const float*)d_in[11];   // [L,EMB,EMB2]
    const float* b1    = (const float*)d_in[12];   // [L,EMB2]
    const float* w2    = (const float*)d_in[13];   // [L,EMB2,EMB]
    const float* b2    = (const float*)d_in[14];   // [L,EMB]
    const float* bng   = (const float*)d_in[15];
    const float* bnb   = (const float*)d_in[16];
    const float* pw1   = (const float*)d_in[17];
    const float* pb1   = (const float*)d_in[18];
    const float* pw2   = (const float*)d_in[19];
    const float* pb2   = (const float*)d_in[20];
    const float* gw    = (const float*)d_in[21];
    const float* gb    = (const float*)d_in[22];
    const float* gcne1 = (const float*)d_in[23];
    const float* gcne2 = (const float*)d_in[24];
    const float* clw   = (const float*)d_in[25];
    const float* clb   = (const float*)d_in[26];
    (void)n_in;

    const int N  = in_sizes[0] / 2;
    const int E  = in_sizes[1] / 2;
    const int FE = in_sizes[4] / 2;
    const int P  = out_size / 2;
    float* outF = (float*)d_out;

    // ---- workspace carve (fits ws_size; P-phase buffers alias agg) ----
    char* wp = (char*)d_ws;
    size_t used = 0;
    auto carve = [&](size_t bytes) {
        char* r = wp;
        size_t a = (bytes + 255) & ~(size_t)255;
        wp += a;
        used += a;
        return r;
    };
    float* h     = (float*)carve((size_t)N * EMB * 4);   // 120 MB
    float* agg   = (float*)carve((size_t)N * EMB * 4);   // 120 MB (reused as h2, then P-phase arena)
    float* stats = (float*)carve(2 * EMB * 4);
    float* cnt   = (float*)carve((size_t)P * 4);
    float* deg   = (float*)carve((size_t)P * 4);
    // adaptive chunk buffer for the 600-wide hidden
    size_t avail = (ws_size > used + (1u << 20)) ? (ws_size - used - (1u << 20)) : 0;
    int CH = (int)(avail / ((size_t)EMB2 * 4));
    if (CH > 25000) CH = 25000;
    if (CH < 512)  CH = 512;   // last-resort floor
    float* t = (float*)carve((size_t)CH * EMB2 * 4);

    // P-phase buffers alias the agg region (dead after last bn_apply).
    // 7 * P*EMB*4 = 84 MB <= 120 MB.
    float* pooled = agg + 0 * (size_t)P * EMB;
    float* tmpP   = agg + 1 * (size_t)P * EMB;
    float* outp   = agg + 2 * (size_t)P * EMB;
    float* f0     = agg + 3 * (size_t)P * EMB;
    float* xw     = agg + 4 * (size_t)P * EMB;
    float* pred   = agg + 5 * (size_t)P * EMB;
    float* f1     = agg + 6 * (size_t)P * EMB;

    const int elemsN  = N * EMB;
    const int gElemsN = cdiv(elemsN, 256);
    const int elemsP  = P * EMB;
    const int gElemsP = cdiv(elemsP, 256);

    // ---- embed ----
    embed_kernel<<<gElemsN, 256, 0, stream>>>(x, atom1, atom2, h, N);

    // ---- 5 GIN layers ----
    for (int l = 0; l < NLAYER; ++l) {
        const float* le1 = ge1 + (size_t)l * 6 * EMB;
        const float* le2 = ge2 + (size_t)l * 3 * EMB;
        agg_init_kernel<<<gElemsN, 256, 0, stream>>>(h, le1, le2, agg, N);
        gin_scatter_kernel<<<cdiv(E, 4), 256, 0, stream>>>(
            h, ei, ei + E, ea, le1, le2, agg, E);
        // MLP, chunked over rows to bound the 600-wide hidden buffer
        for (int c0 = 0; c0 < N; c0 += CH) {
            int rows = min(CH, N - c0);
            dim3 g1(cdiv(EMB2, TS), cdiv(rows, TS));
            gemm_bias_act<<<g1, 256, 0, stream>>>(
                agg + (size_t)c0 * EMB, w1 + (size_t)l * EMB * EMB2,
                b1 + (size_t)l * EMB2, t, rows, EMB, EMB2, 1);
            dim3 g2(cdiv(EMB, TS), cdiv(rows, TS));
            gemm_bias_act<<<g2, 256, 0, stream>>>(
                t, w2 + (size_t)l * EMB2 * EMB, b2 + (size_t)l * EMB,
                agg + (size_t)c0 * EMB, rows, EMB2, EMB, 0);
        }
        launch_zero(stats, 2 * EMB, stream);
        bn_stats_kernel<<<256, 320, 0, stream>>>(agg, stats, N, cdiv(N, 256));
        bn_apply_kernel<<<gElemsN, 256, 0, stream>>>(
            agg, stats, bng + (size_t)l * EMB, bnb + (size_t)l * EMB, h, N,
            (l < NLAYER - 1) ? 1 : 0, 1.f / (float)N);
    }

    // ---- fragment mean pool (agg region now dead -> P-phase arena) ----
    launch_zero(pooled, (size_t)P * EMB, stream);
    launch_zero(cnt, (size_t)P, stream);
    pool_scatter_kernel<<<cdiv(N, 4), 256, 0, stream>>>(h, fb, pooled, cnt, N);
    pool_div_kernel<<<gElemsP, 256, 0, stream>>>(pooled, cnt, P);

    // ---- projector MLP + normalize ----
    {
        dim3 g1(cdiv(EMB, TS), cdiv(P, TS));
        gemm_bias_act<<<g1, 256, 0, stream>>>(pooled, pw1, pb1, tmpP, P, EMB, EMB, 1);
        gemm_bias_act<<<g1, 256, 0, stream>>>(tmpP, pw2, pb2, outp, P, EMB, EMB, 0);
        normalize_rows_kernel<<<cdiv(P, 4), 256, 0, stream>>>(outp, f0, P);
    }

    // ---- GCN predictor ----
    {
        dim3 g1(cdiv(EMB, TS), cdiv(P, TS));
        gemm_bias_act<<<g1, 256, 0, stream>>>(outp, gw, gb, xw, P, EMB, EMB, 0);
        launch_zero(deg, (size_t)P, stream);
        launch_zero(pred, (size_t)P * EMB, stream);
        deg_kernel<<<cdiv(2 * FE, 256), 256, 0, stream>>>(fei, deg, FE);
        gcn_scatter_kernel<<<cdiv(2 * FE, 4), 256, 0, stream>>>(
            xw, fei, dea, gcne1, gcne2, deg, pred, FE);
        normalize_rows_kernel<<<cdiv(P, 4), 256, 0, stream>>>(pred, f1, P);
    }

    // ---- classifier ----
    classifier_kernel<<<cdiv(2 * P, 4), 256, 0, stream>>>(f0, f1, clw, clb, outF, P);
}

// Round 3
// 10218.172 us; speedup vs baseline: 1.2240x; 1.2240x over previous
//
#include <hip/hip_runtime.h>
#include <cstdint>
#include <cstddef>

#define EMB 300
#define EMB2 600
#define NLAYER 5
#define KP1 320     // padded K for GIN GEMM1 (300 -> 320)
#define NP1 640     // padded N for GEMM1 out / K for GEMM2 (600 -> 640)
#define NP2 384     // padded N-tiles for GEMM2 out (300 -> 3*128)

typedef short bf16x8 __attribute__((ext_vector_type(8)));
typedef float f32x4 __attribute__((ext_vector_type(4)));
typedef unsigned short ushort_t;

static inline int cdiv(int a, int b) { return (a + b - 1) / b; }

__device__ inline ushort_t f2bf(float v) {
    unsigned u = __float_as_uint(v);
    u += 0x7fffu + ((u >> 16) & 1u);
    return (ushort_t)(u >> 16);
}
__device__ inline float bf2f(ushort_t h) { return __uint_as_float(((unsigned)h) << 16); }

// ---------------- zero fill (capture-safe) ----------------
__global__ __launch_bounds__(256) void zero_kernel(float* __restrict__ p, size_t n)
{
    size_t i = (size_t)blockIdx.x * blockDim.x + threadIdx.x;
    size_t stride = (size_t)gridDim.x * blockDim.x;
    for (; i < n; i += stride) p[i] = 0.f;
}
static inline void launch_zero(float* p, size_t n, hipStream_t s)
{
    int g = (int)((n + 255) / 256);
    if (g > 2048) g = 2048;
    zero_kernel<<<g, 256, 0, s>>>(p, n);
}

// ---------------- embed ----------------
__global__ __launch_bounds__(256) void embed_kernel(
    const int* __restrict__ x, const float* __restrict__ a1,
    const float* __restrict__ a2, float* __restrict__ h, int N)
{
    int idx = blockIdx.x * blockDim.x + threadIdx.x;
    if (idx >= N * EMB) return;
    int row = idx / EMB, col = idx % EMB;
    h[idx] = a1[x[2 * row] * EMB + col] + a2[x[2 * row + 1] * EMB + col];
}

// ---------------- agg = h + selfloop ----------------
__global__ __launch_bounds__(256) void agg_init_kernel(
    const float* __restrict__ h, const float* __restrict__ e1,
    const float* __restrict__ e2, float* __restrict__ agg, int N)
{
    int idx = blockIdx.x * blockDim.x + threadIdx.x;
    if (idx >= N * EMB) return;
    int col = idx % EMB;
    agg[idx] = h[idx] + e1[4 * EMB + col] + e2[col];
}

// ---------------- GIN edge scatter ----------------
__global__ __launch_bounds__(256) void gin_scatter_kernel(
    const float* __restrict__ h, const int* __restrict__ src,
    const int* __restrict__ dst, const int* __restrict__ ea,
    const float* __restrict__ e1, const float* __restrict__ e2,
    float* __restrict__ agg, int E)
{
    int wv = (blockIdx.x * blockDim.x + threadIdx.x) >> 6;
    int lane = threadIdx.x & 63;
    if (wv >= E) return;
    int s = src[wv], d = dst[wv];
    int a0 = ea[2 * wv], a1 = ea[2 * wv + 1];
    const float* hs = h + (size_t)s * EMB;
    const float* t1 = e1 + (size_t)a0 * EMB;
    const float* t2 = e2 + (size_t)a1 * EMB;
    float* ad = agg + (size_t)d * EMB;
    for (int c = lane; c < EMB; c += 64)
        atomicAdd(&ad[c], hs[c] + t1[c] + t2[c]);
}

// ---------------- fp32 -> (hi,lo) bf16 split, padded ----------------
// src pre-offset to chunk start. dst is [rows_total][dst_ld].
__global__ __launch_bounds__(256) void split_kernel(
    const float* __restrict__ src, int src_ld, int rows_valid, int cols_valid,
    ushort_t* __restrict__ hi, ushort_t* __restrict__ lo, int dst_ld, int rows_total)
{
    int idx = blockIdx.x * 256 + threadIdx.x;
    if (idx >= rows_total * dst_ld) return;
    int r = idx / dst_ld, k = idx - r * dst_ld;
    float v = (r < rows_valid && k < cols_valid) ? src[(size_t)r * src_ld + k] : 0.f;
    ushort_t h = f2bf(v);
    hi[idx] = h;
    lo[idx] = f2bf(v - bf2f(h));
}

// ---------------- weight transpose + split: W[K][Nc] -> Wt_{hi,lo}[Npad][Kpad] ----------------
__global__ __launch_bounds__(256) void wsplit_kernel(
    const float* __restrict__ W, int K, int Nc,
    ushort_t* __restrict__ hi, ushort_t* __restrict__ lo, int Kpad, int Npad)
{
    int idx = blockIdx.x * 256 + threadIdx.x;
    if (idx >= Npad * Kpad) return;
    int n = idx / Kpad, k = idx - n * Kpad;
    float v = (n < Nc && k < K) ? W[(size_t)k * Nc + n] : 0.f;
    ushort_t h = f2bf(v);
    hi[idx] = h;
    lo[idx] = f2bf(v - bf2f(h));
}

// ---------------- bf16x3 MFMA GEMM ----------------
// C[M,N] = act(A[M,K] @ B[K,N] + bias), A given as hi/lo planes [*][lda],
// B given TRANSPOSED as hi/lo planes [N][ldb]. K multiple of 32; grid covers
// 128x128 tiles; col tiles fully padded in B, row tiles fully padded in A.
__global__ __launch_bounds__(256) void gemm_mfma3(
    const ushort_t* __restrict__ Ahi, const ushort_t* __restrict__ Alo, int lda,
    const ushort_t* __restrict__ Bhi, const ushort_t* __restrict__ Blo, int ldb,
    const float* __restrict__ bias, int K, int Mvalid, int Nvalid,
    float* __restrict__ Cf, int ldc_f,
    ushort_t* __restrict__ Chi, ushort_t* __restrict__ Clo, int ldc_s,
    int relu, int split_out)
{
    // LDS rows padded to 40 ushorts: frag ds_read_b128 slot = (5*row+c)%8 -> 2-way (free)
    __shared__ ushort_t As[2][128][40];
    __shared__ ushort_t Bs[2][128][40];
    const int tid = threadIdx.x;
    const int lane = tid & 63, wid = tid >> 6;
    const int wr = wid >> 1, wc = wid & 1;          // 2x2 waves, 64x64 each
    const int lr = lane & 15, ko = (lane >> 4) * 8; // fragment row/col + k offset
    const int row0 = blockIdx.y * 128, col0 = blockIdx.x * 128;
    const int srow = tid >> 1;            // staging row 0..127
    const int sc0 = (tid & 1) * 2;        // staging chunks sc0, sc0+1 (8 bf16 each)

    f32x4 acc[4][4] = {};
    bf16x8 rgA0, rgA1, rgA2, rgA3, rgB0, rgB1, rgB2, rgB3;

    const ushort_t* pAhi = Ahi + (size_t)(row0 + srow) * lda + sc0 * 8;
    const ushort_t* pAlo = Alo + (size_t)(row0 + srow) * lda + sc0 * 8;
    const ushort_t* pBhi = Bhi + (size_t)(col0 + srow) * ldb + sc0 * 8;
    const ushort_t* pBlo = Blo + (size_t)(col0 + srow) * ldb + sc0 * 8;

    // prologue loads (k0 = 0)
    rgA0 = *(const bf16x8*)(pAhi);     rgA1 = *(const bf16x8*)(pAhi + 8);
    rgA2 = *(const bf16x8*)(pAlo);     rgA3 = *(const bf16x8*)(pAlo + 8);
    rgB0 = *(const bf16x8*)(pBhi);     rgB1 = *(const bf16x8*)(pBhi + 8);
    rgB2 = *(const bf16x8*)(pBlo);     rgB3 = *(const bf16x8*)(pBlo + 8);

    for (int k0 = 0; k0 < K; k0 += 32) {
        *(bf16x8*)&As[0][srow][sc0 * 8]     = rgA0;
        *(bf16x8*)&As[0][srow][sc0 * 8 + 8] = rgA1;
        *(bf16x8*)&As[1][srow][sc0 * 8]     = rgA2;
        *(bf16x8*)&As[1][srow][sc0 * 8 + 8] = rgA3;
        *(bf16x8*)&Bs[0][srow][sc0 * 8]     = rgB0;
        *(bf16x8*)&Bs[0][srow][sc0 * 8 + 8] = rgB1;
        *(bf16x8*)&Bs[1][srow][sc0 * 8]     = rgB2;
        *(bf16x8*)&Bs[1][srow][sc0 * 8 + 8] = rgB3;
        __syncthreads();
        if (k0 + 32 < K) {   // issue next-tile global loads early; latency hides under MFMAs
            int kn = k0 + 32;
            rgA0 = *(const bf16x8*)(pAhi + kn);     rgA1 = *(const bf16x8*)(pAhi + kn + 8);
            rgA2 = *(const bf16x8*)(pAlo + kn);     rgA3 = *(const bf16x8*)(pAlo + kn + 8);
            rgB0 = *(const bf16x8*)(pBhi + kn);     rgB1 = *(const bf16x8*)(pBhi + kn + 8);
            rgB2 = *(const bf16x8*)(pBlo + kn);     rgB3 = *(const bf16x8*)(pBlo + kn + 8);
        }
        bf16x8 afh[4], afl[4], bfh[4], bfl[4];
        #pragma unroll
        for (int f = 0; f < 4; ++f) {
            int ar = wr * 64 + f * 16 + lr;
            afh[f] = *(const bf16x8*)&As[0][ar][ko];
            afl[f] = *(const bf16x8*)&As[1][ar][ko];
            int bc = wc * 64 + f * 16 + lr;
            bfh[f] = *(const bf16x8*)&Bs[0][bc][ko];
            bfl[f] = *(const bf16x8*)&Bs[1][bc][ko];
        }
        #pragma unroll
        for (int f = 0; f < 4; ++f)
            #pragma unroll
            for (int g = 0; g < 4; ++g) {
                acc[f][g] = __builtin_amdgcn_mfma_f32_16x16x32_bf16(afh[f], bfh[g], acc[f][g], 0, 0, 0);
                acc[f][g] = __builtin_amdgcn_mfma_f32_16x16x32_bf16(afh[f], bfl[g], acc[f][g], 0, 0, 0);
                acc[f][g] = __builtin_amdgcn_mfma_f32_16x16x32_bf16(afl[f], bfh[g], acc[f][g], 0, 0, 0);
            }
        __syncthreads();
    }

    // epilogue: C/D mapping col=lane&15, row=(lane>>4)*4+reg  [m89-verified]
    #pragma unroll
    for (int f = 0; f < 4; ++f) {
        int grb = row0 + wr * 64 + f * 16 + (lane >> 4) * 4;
        #pragma unroll
        for (int g = 0; g < 4; ++g) {
            int gc = col0 + wc * 64 + g * 16 + lr;
            float bv = (gc < Nvalid) ? bias[gc] : 0.f;
            #pragma unroll
            for (int j = 0; j < 4; ++j) {
                int gr = grb + j;
                float v = acc[f][g][j] + bv;
                if (relu) v = fmaxf(v, 0.f);
                if (split_out) {
                    if (gc >= Nvalid) v = 0.f;   // keep K-pad region zero for next GEMM
                    size_t o = (size_t)gr * ldc_s + gc;
                    ushort_t hh = f2bf(v);
                    Chi[o] = hh;
                    Clo[o] = f2bf(v - bf2f(hh));
                } else {
                    if (gr < Mvalid && gc < Nvalid)
                        Cf[(size_t)gr * ldc_f + gc] = v;
                }
            }
        }
    }
}

// ---------------- fp32 GEMM (P-phase only) ----------------
#define TS 64
#define BKK 16
__global__ __launch_bounds__(256) void gemm_bias_act(
    const float* __restrict__ A, const float* __restrict__ W,
    const float* __restrict__ bias, float* __restrict__ C,
    int M, int K, int Nc, int relu_flag)
{
    __shared__ float Asm[BKK][TS + 4];
    __shared__ float Bsm[BKK][TS + 4];
    const int tid = threadIdx.x;
    const int tx = tid & 15, ty = tid >> 4;
    const int row0 = blockIdx.y * TS, col0 = blockIdx.x * TS;
    const int lka = tid & 15, lra = tid >> 4;
    const int lnb = tid & 63, lkb = tid >> 6;
    float acc[4][4] = {};
    for (int k0 = 0; k0 < K; k0 += BKK) {
        #pragma unroll
        for (int i = 0; i < 4; ++i) {
            int rr = lra + 16 * i;
            int gr = row0 + rr, gk = k0 + lka;
            Asm[lka][rr] = (gr < M && gk < K) ? A[(size_t)gr * K + gk] : 0.f;
        }
        #pragma unroll
        for (int i = 0; i < 4; ++i) {
            int kk = lkb + 4 * i;
            int gk = k0 + kk, gn = col0 + lnb;
            Bsm[kk][lnb] = (gk < K && gn < Nc) ? W[(size_t)gk * Nc + gn] : 0.f;
        }
        __syncthreads();
        #pragma unroll
        for (int kk = 0; kk < BKK; ++kk) {
            float a[4], b[4];
            #pragma unroll
            for (int i = 0; i < 4; ++i) a[i] = Asm[kk][ty * 4 + i];
            #pragma unroll
            for (int j = 0; j < 4; ++j) b[j] = Bsm[kk][tx * 4 + j];
            #pragma unroll
            for (int i = 0; i < 4; ++i)
                #pragma unroll
                for (int j = 0; j < 4; ++j)
                    acc[i][j] = fmaf(a[i], b[j], acc[i][j]);
        }
        __syncthreads();
    }
    #pragma unroll
    for (int i = 0; i < 4; ++i) {
        int gr = row0 + ty * 4 + i;
        if (gr >= M) continue;
        #pragma unroll
        for (int j = 0; j < 4; ++j) {
            int gn = col0 + tx * 4 + j;
            if (gn >= Nc) continue;
            float v = acc[i][j] + bias[gn];
            if (relu_flag) v = fmaxf(v, 0.f);
            C[(size_t)gr * Nc + gn] = v;
        }
    }
}

// ---------------- BN stats ----------------
__global__ __launch_bounds__(320) void bn_stats_kernel(
    const float* __restrict__ H, float* __restrict__ stats, int M, int rpb)
{
    int col = threadIdx.x;
    if (col >= EMB) return;
    int r0 = blockIdx.x * rpb;
    int r1 = min(M, r0 + rpb);
    float s = 0.f, s2 = 0.f;
    for (int r = r0; r < r1; ++r) {
        float v = H[(size_t)r * EMB + col];
        s += v;
        s2 = fmaf(v, v, s2);
    }
    atomicAdd(&stats[col], s);
    atomicAdd(&stats[EMB + col], s2);
}

// ---------------- BN apply ----------------
__global__ __launch_bounds__(256) void bn_apply_kernel(
    const float* __restrict__ h2, const float* __restrict__ stats,
    const float* __restrict__ g, const float* __restrict__ b,
    float* __restrict__ hout, int N, int relu_flag, float invN)
{
    int idx = blockIdx.x * blockDim.x + threadIdx.x;
    if (idx >= N * EMB) return;
    int col = idx % EMB;
    float mu = stats[col] * invN;
    float var = fmaf(-mu, mu, stats[EMB + col] * invN);
    float v = (h2[idx] - mu) * rsqrtf(var + 1e-5f) * g[col] + b[col];
    if (relu_flag) v = fmaxf(v, 0.f);
    hout[idx] = v;
}

// ---------------- fragment pool ----------------
__global__ __launch_bounds__(256) void pool_scatter_kernel(
    const float* __restrict__ h, const int* __restrict__ fb,
    float* __restrict__ pooled, float* __restrict__ cnt, int N)
{
    int wv = (blockIdx.x * blockDim.x + threadIdx.x) >> 6;
    int lane = threadIdx.x & 63;
    if (wv >= N) return;
    int p = fb[wv];
    const float* hr = h + (size_t)wv * EMB;
    float* pr = pooled + (size_t)p * EMB;
    for (int c = lane; c < EMB; c += 64) atomicAdd(&pr[c], hr[c]);
    if (lane == 0) atomicAdd(&cnt[p], 1.f);
}

__global__ __launch_bounds__(256) void pool_div_kernel(
    float* __restrict__ pooled, const float* __restrict__ cnt, int P)
{
    int idx = blockIdx.x * blockDim.x + threadIdx.x;
    if (idx >= P * EMB) return;
    pooled[idx] /= fmaxf(cnt[idx / EMB], 1.f);
}

// ---------------- row L2 normalize ----------------
__global__ __launch_bounds__(256) void normalize_rows_kernel(
    const float* __restrict__ X, float* __restrict__ Y, int M)
{
    int wv = (blockIdx.x * blockDim.x + threadIdx.x) >> 6;
    int lane = threadIdx.x & 63;
    if (wv >= M) return;
    const float* x = X + (size_t)wv * EMB;
    float ss = 0.f;
    for (int c = lane; c < EMB; c += 64) { float v = x[c]; ss = fmaf(v, v, ss); }
    #pragma unroll
    for (int o = 32; o > 0; o >>= 1) ss += __shfl_xor(ss, o, 64);
    float inv = 1.f / fmaxf(sqrtf(ss), 1e-12f);
    float* y = Y + (size_t)wv * EMB;
    for (int c = lane; c < EMB; c += 64) y[c] = x[c] * inv;
}

// ---------------- GCN ----------------
__global__ __launch_bounds__(256) void deg_kernel(
    const int* __restrict__ fei, float* __restrict__ deg, int FE)
{
    int i = blockIdx.x * blockDim.x + threadIdx.x;
    if (i < 2 * FE) atomicAdd(&deg[fei[i]], 1.f);
}

__global__ __launch_bounds__(256) void gcn_scatter_kernel(
    const float* __restrict__ xw, const int* __restrict__ fei,
    const int* __restrict__ dea, const float* __restrict__ e1,
    const float* __restrict__ e2, const float* __restrict__ deg,
    float* __restrict__ pred, int FE)
{
    int i = (blockIdx.x * blockDim.x + threadIdx.x) >> 6;
    int lane = threadIdx.x & 63;
    if (i >= 2 * FE) return;
    int u = fei[i];
    int v = (i < FE) ? fei[i + FE] : fei[i - FE];
    int er = (i < FE) ? i : i - FE;
    int a0 = dea[2 * er], a1 = dea[2 * er + 1];
    float du = deg[u], dv = deg[v];
    float su = du > 0.f ? rsqrtf(fmaxf(du, 1.f)) : 0.f;
    float sv = dv > 0.f ? rsqrtf(fmaxf(dv, 1.f)) : 0.f;
    float nr = su * sv;
    const float* xu = xw + (size_t)u * EMB;
    const float* t1 = e1 + (size_t)a0 * EMB;
    const float* t2 = e2 + (size_t)a1 * EMB;
    float* pv = pred + (size_t)v * EMB;
    for (int c = lane; c < EMB; c += 64)
        atomicAdd(&pv[c], nr * (xu[c] + t1[c] + t2[c]));
}

// ---------------- classifier ----------------
__global__ __launch_bounds__(256) void classifier_kernel(
    const float* __restrict__ f0, const float* __restrict__ f1,
    const float* __restrict__ w, const float* __restrict__ b,
    float* __restrict__ out, int P)
{
    int q = (blockIdx.x * blockDim.x + threadIdx.x) >> 6;
    int lane = threadIdx.x & 63;
    if (q >= 2 * P) return;
    int i = (q < P) ? q : q - P;
    int j = (q < P) ? i : (i == 0 ? P - 1 : i - 1);
    const float* a = f0 + (size_t)i * EMB;
    const float* c = f1 + (size_t)j * EMB;
    float s = 0.f;
    for (int k = lane; k < EMB; k += 64) s = fmaf(fmaxf(a[k], c[k]), w[k], s);
    #pragma unroll
    for (int o = 32; o > 0; o >>= 1) s += __shfl_xor(s, o, 64);
    if (lane == 0) out[q] = s + b[0];
}

extern "C" void kernel_launch(void* const* d_in, const int* in_sizes, int n_in,
                              void* d_out, int out_size, void* d_ws, size_t ws_size,
                              hipStream_t stream)
{
    const int*   x     = (const int*)d_in[0];
    const int*   ei    = (const int*)d_in[1];
    const int*   ea    = (const int*)d_in[2];
    const int*   fb    = (const int*)d_in[3];
    const int*   fei   = (const int*)d_in[4];
    const int*   dea   = (const int*)d_in[5];
    const float* atom1 = (const float*)d_in[7];
    const float* atom2 = (const float*)d_in[8];
    const float* ge1   = (const float*)d_in[9];
    const float* ge2   = (const float*)d_in[10];
    const float* w1    = (const float*)d_in[11];
    const float* b1    = (const float*)d_in[12];
    const float* w2    = (const float*)d_in[13];
    const float* b2    = (const float*)d_in[14];
    const float* bng   = (const float*)d_in[15];
    const float* bnb   = (const float*)d_in[16];
    const float* pw1   = (const float*)d_in[17];
    const float* pb1   = (const float*)d_in[18];
    const float* pw2   = (const float*)d_in[19];
    const float* pb2   = (const float*)d_in[20];
    const float* gw    = (const float*)d_in[21];
    const float* gb    = (const float*)d_in[22];
    const float* gcne1 = (const float*)d_in[23];
    const float* gcne2 = (const float*)d_in[24];
    const float* clw   = (const float*)d_in[25];
    const float* clb   = (const float*)d_in[26];
    (void)n_in;

    const int N  = in_sizes[0] / 2;
    const int E  = in_sizes[1] / 2;
    const int FE = in_sizes[4] / 2;
    const int P  = out_size / 2;
    float* outF = (float*)d_out;

    // ---- workspace carve ----
    char* wp = (char*)d_ws;
    size_t used = 0;
    auto carve = [&](size_t bytes) -> char* {
        char* r = wp;
        size_t a = (bytes + 255) & ~(size_t)255;
        wp += a;
        used += a;
        return r;
    };
    float* h     = (float*)carve((size_t)N * EMB * 4);   // 120 MB
    float* agg   = (float*)carve((size_t)N * EMB * 4);   // 120 MB; P-phase arena later
    float* stats = (float*)carve(2 * EMB * 4);
    float* cnt   = (float*)carve((size_t)P * 4);
    float* deg   = (float*)carve((size_t)P * 4);
    // split weights: per layer w1t (NP1 x KP1) hi/lo + w2t (NP2 x NP1) hi/lo
    ushort_t* w1t_hi[NLAYER]; ushort_t* w1t_lo[NLAYER];
    ushort_t* w2t_hi[NLAYER]; ushort_t* w2t_lo[NLAYER];
    for (int l = 0; l < NLAYER; ++l) {
        w1t_hi[l] = (ushort_t*)carve((size_t)NP1 * KP1 * 2);
        w1t_lo[l] = (ushort_t*)carve((size_t)NP1 * KP1 * 2);
        w2t_hi[l] = (ushort_t*)carve((size_t)NP2 * NP1 * 2);
        w2t_lo[l] = (ushort_t*)carve((size_t)NP2 * NP1 * 2);
    }
    // adaptive chunk: per-row bytes = a planes (2*KP1*2) + t planes (2*NP1*2) = 3840
    size_t avail = (ws_size > used + (2u << 20)) ? (ws_size - used - (2u << 20)) : 0;
    long long chl = (long long)(avail / 3840);
    int Mfull_t = cdiv(N, 128) * 128;
    int CH = (int)((chl > Mfull_t) ? Mfull_t : chl);
    CH &= ~127;
    if (CH < 128) CH = 128;
    ushort_t* a_hi = (ushort_t*)carve((size_t)CH * KP1 * 2);
    ushort_t* a_lo = (ushort_t*)carve((size_t)CH * KP1 * 2);
    ushort_t* t_hi = (ushort_t*)carve((size_t)CH * NP1 * 2);
    ushort_t* t_lo = (ushort_t*)carve((size_t)CH * NP1 * 2);

    // P-phase buffers alias agg (dead after last bn_apply): 7 * P*EMB*4 = 84 MB <= 120 MB
    float* pooled = agg + 0 * (size_t)P * EMB;
    float* tmpP   = agg + 1 * (size_t)P * EMB;
    float* outp   = agg + 2 * (size_t)P * EMB;
    float* f0     = agg + 3 * (size_t)P * EMB;
    float* xw     = agg + 4 * (size_t)P * EMB;
    float* pred   = agg + 5 * (size_t)P * EMB;
    float* f1     = agg + 6 * (size_t)P * EMB;

    const int gElemsN = cdiv(N * EMB, 256);
    const int gElemsP = cdiv(P * EMB, 256);

    // ---- split weights (cheap; runs every call for determinism) ----
    for (int l = 0; l < NLAYER; ++l) {
        wsplit_kernel<<<cdiv(NP1 * KP1, 256), 256, 0, stream>>>(
            w1 + (size_t)l * EMB * EMB2, EMB, EMB2, w1t_hi[l], w1t_lo[l], KP1, NP1);
        wsplit_kernel<<<cdiv(NP2 * NP1, 256), 256, 0, stream>>>(
            w2 + (size_t)l * EMB2 * EMB, EMB2, EMB, w2t_hi[l], w2t_lo[l], NP1, NP2);
    }

    // ---- embed ----
    embed_kernel<<<gElemsN, 256, 0, stream>>>(x, atom1, atom2, h, N);

    // ---- 5 GIN layers ----
    for (int l = 0; l < NLAYER; ++l) {
        const float* le1 = ge1 + (size_t)l * 6 * EMB;
        const float* le2 = ge2 + (size_t)l * 3 * EMB;
        agg_init_kernel<<<gElemsN, 256, 0, stream>>>(h, le1, le2, agg, N);
        gin_scatter_kernel<<<cdiv(E, 4), 256, 0, stream>>>(
            h, ei, ei + E, ea, le1, le2, agg, E);
        for (int c0 = 0; c0 < N; c0 += CH) {
            int rows = min(CH, N - c0);
            int Mt = cdiv(rows, 128);
            split_kernel<<<cdiv(Mt * 128 * KP1, 256), 256, 0, stream>>>(
                agg + (size_t)c0 * EMB, EMB, rows, EMB, a_hi, a_lo, KP1, Mt * 128);
            gemm_mfma3<<<dim3(NP1 / 128, Mt), 256, 0, stream>>>(
                a_hi, a_lo, KP1, w1t_hi[l], w1t_lo[l], KP1,
                b1 + (size_t)l * EMB2, KP1, Mt * 128, EMB2,
                nullptr, 0, t_hi, t_lo, NP1, 1, 1);
            gemm_mfma3<<<dim3(NP2 / 128, Mt), 256, 0, stream>>>(
                t_hi, t_lo, NP1, w2t_hi[l], w2t_lo[l], NP1,
                b2 + (size_t)l * EMB, NP1, rows, EMB,
                agg + (size_t)c0 * EMB, EMB, nullptr, nullptr, 0, 0, 0);
        }
        launch_zero(stats, 2 * EMB, stream);
        bn_stats_kernel<<<256, 320, 0, stream>>>(agg, stats, N, cdiv(N, 256));
        bn_apply_kernel<<<gElemsN, 256, 0, stream>>>(
            agg, stats, bng + (size_t)l * EMB, bnb + (size_t)l * EMB, h, N,
            (l < NLAYER - 1) ? 1 : 0, 1.f / (float)N);
    }

    // ---- fragment mean pool ----
    launch_zero(pooled, (size_t)P * EMB, stream);
    launch_zero(cnt, (size_t)P, stream);
    pool_scatter_kernel<<<cdiv(N, 4), 256, 0, stream>>>(h, fb, pooled, cnt, N);
    pool_div_kernel<<<gElemsP, 256, 0, stream>>>(pooled, cnt, P);

    // ---- projector MLP + normalize ----
    {
        dim3 g1(cdiv(EMB, TS), cdiv(P, TS));
        gemm_bias_act<<<g1, 256, 0, stream>>>(pooled, pw1, pb1, tmpP, P, EMB, EMB, 1);
        gemm_bias_act<<<g1, 256, 0, stream>>>(tmpP, pw2, pb2, outp, P, EMB, EMB, 0);
        normalize_rows_kernel<<<cdiv(P, 4), 256, 0, stream>>>(outp, f0, P);
    }

    // ---- GCN predictor ----
    {
        dim3 g1(cdiv(EMB, TS), cdiv(P, TS));
        gemm_bias_act<<<g1, 256, 0, stream>>>(outp, gw, gb, xw, P, EMB, EMB, 0);
        launch_zero(deg, (size_t)P, stream);
        launch_zero(pred, (size_t)P * EMB, stream);
        deg_kernel<<<cdiv(2 * FE, 256), 256, 0, stream>>>(fei, deg, FE);
        gcn_scatter_kernel<<<cdiv(2 * FE, 4), 256, 0, stream>>>(
            xw, fei, dea, gcne1, gcne2, deg, pred, FE);
        normalize_rows_kernel<<<cdiv(P, 4), 256, 0, stream>>>(pred, f1, P);
    }

    // ---- classifier ----
    classifier_kernel<<<cdiv(2 * P, 4), 256, 0, stream>>>(f0, f1, clw, clb, outF, P);
}

// Round 4
// 7248.705 us; speedup vs baseline: 1.7254x; 1.4097x over previous
//
#include <hip/hip_runtime.h>
#include <cstdint>
#include <cstddef>

#define EMB 300
#define EMB2 600
#define NLAYER 5
#define KP1 320     // padded K for GIN GEMM1 (300 -> 320)
#define NP1 640     // padded N for GEMM1 out / K for GEMM2 (600 -> 640)
#define NP2 384     // padded N-tile cover for GEMM2 out (300 -> 3*128)
#define SCAN_B 256

typedef short bf16x8 __attribute__((ext_vector_type(8)));
typedef float f32x4 __attribute__((ext_vector_type(4)));
typedef unsigned short ushort_t;

static inline int cdiv(int a, int b) { return (a + b - 1) / b; }

__device__ inline ushort_t f2bf(float v) {
    unsigned u = __float_as_uint(v);
    u += 0x7fffu + ((u >> 16) & 1u);
    return (ushort_t)(u >> 16);
}
__device__ inline float bf2f(ushort_t h) { return __uint_as_float(((unsigned)h) << 16); }

// ---------------- zero fill (capture-safe) ----------------
__global__ __launch_bounds__(256) void zero_kernel(float* __restrict__ p, size_t n)
{
    size_t i = (size_t)blockIdx.x * blockDim.x + threadIdx.x;
    size_t stride = (size_t)gridDim.x * blockDim.x;
    for (; i < n; i += stride) p[i] = 0.f;
}
static inline void launch_zero(float* p, size_t n, hipStream_t s)
{
    int g = (int)((n + 255) / 256);
    if (g > 2048) g = 2048;
    zero_kernel<<<g, 256, 0, s>>>(p, n);
}
__global__ __launch_bounds__(256) void izero_kernel(int* __restrict__ p, int n)
{
    int i = blockIdx.x * 256 + threadIdx.x;
    if (i < n) p[i] = 0;
}

// ---------------- embed ----------------
__global__ __launch_bounds__(256) void embed_kernel(
    const int* __restrict__ x, const float* __restrict__ a1,
    const float* __restrict__ a2, float* __restrict__ h, int N)
{
    int idx = blockIdx.x * blockDim.x + threadIdx.x;
    if (idx >= N * EMB) return;
    int row = idx / EMB, col = idx % EMB;
    h[idx] = a1[x[2 * row] * EMB + col] + a2[x[2 * row + 1] * EMB + col];
}

// ---------------- CSR build: count / scan / fill ----------------
__global__ __launch_bounds__(256) void count_kernel(
    const int* __restrict__ dst, int* __restrict__ cnt, int E)
{
    int e = blockIdx.x * 256 + threadIdx.x;
    if (e < E) atomicAdd(&cnt[dst[e]], 1);
}

__global__ __launch_bounds__(SCAN_B) void scan_block_kernel(
    const int* __restrict__ in, int* __restrict__ out, int* __restrict__ bsum, int n)
{
    __shared__ int s[SCAN_B];
    int t = threadIdx.x, i = blockIdx.x * SCAN_B + t;
    int v = (i < n) ? in[i] : 0;
    s[t] = v; __syncthreads();
    for (int o = 1; o < SCAN_B; o <<= 1) {
        int xv = (t >= o) ? s[t - o] : 0;
        __syncthreads();
        s[t] += xv;
        __syncthreads();
    }
    if (i < n) out[i] = s[t] - v;           // exclusive
    if (t == SCAN_B - 1) bsum[blockIdx.x] = s[t];
}

__global__ __launch_bounds__(512) void scan_partials_kernel(
    const int* __restrict__ bsum, int* __restrict__ bbase, int nb)
{
    __shared__ int s[512];
    int t = threadIdx.x;
    int v = (t < nb) ? bsum[t] : 0;
    s[t] = v; __syncthreads();
    for (int o = 1; o < 512; o <<= 1) {
        int xv = (t >= o) ? s[t - o] : 0;
        __syncthreads();
        s[t] += xv;
        __syncthreads();
    }
    if (t < nb) bbase[t] = s[t] - v;        // exclusive
}

__global__ __launch_bounds__(256) void scan_add_kernel(
    int* __restrict__ off, const int* __restrict__ bbase, int n, int total)
{
    int i = blockIdx.x * 256 + threadIdx.x;
    if (i < n) off[i] += bbase[i / SCAN_B];
    if (i == 0) off[n] = total;
}

__global__ __launch_bounds__(256) void fill_kernel(
    const int* __restrict__ dst, const int* __restrict__ off,
    int* __restrict__ cursor, int* __restrict__ eid, int E)
{
    int e = blockIdx.x * 256 + threadIdx.x;
    if (e >= E) return;
    int d = dst[e];
    int p = atomicAdd(&cursor[d], 1);
    eid[off[d] + p] = e;
}

// ---------------- per-layer edge-emb combo table: E12[a0*3+a1] = e1[a0]+e2[a1] ----------------
__global__ __launch_bounds__(256) void e12_kernel(
    const float* __restrict__ e1, const float* __restrict__ e2, float* __restrict__ E12)
{
    int idx = blockIdx.x * 256 + threadIdx.x;
    if (idx >= 18 * EMB) return;
    int cmb = idx / EMB, c = idx - cmb * EMB;
    E12[idx] = e1[(cmb / 3) * EMB + c] + e2[(cmb % 3) * EMB + c];
}

// ---------------- GIN gather (CSR): agg[d] = h[d] + self + sum_in(h[src]+E12[cmb]) ----------------
__global__ __launch_bounds__(256) void gin_gather_kernel(
    const float* __restrict__ h, const int* __restrict__ off,
    const int* __restrict__ eid, const int* __restrict__ src,
    const int* __restrict__ ea, const float* __restrict__ E12,
    float* __restrict__ agg, int N)
{
    int node = (blockIdx.x * blockDim.x + threadIdx.x) >> 6;
    int lane = threadIdx.x & 63;
    if (node >= N) return;
    const float* selfrow = E12 + 12 * EMB;   // (a0=4, a1=0)
    const float* hn = h + (size_t)node * EMB;
    float acc[5];
    #pragma unroll
    for (int r = 0; r < 5; ++r) {
        int c = lane + r * 64;
        acc[r] = (c < EMB) ? hn[c] + selfrow[c] : 0.f;
    }
    int j1 = off[node + 1];
    for (int j = off[node]; j < j1; ++j) {
        int e = eid[j];
        int s = src[e];
        int cmb = ea[2 * e] * 3 + ea[2 * e + 1];
        const float* hs = h + (size_t)s * EMB;
        const float* er = E12 + (size_t)cmb * EMB;
        #pragma unroll
        for (int r = 0; r < 5; ++r) {
            int c = lane + r * 64;
            if (c < EMB) acc[r] += hs[c] + er[c];
        }
    }
    float* ag = agg + (size_t)node * EMB;
    #pragma unroll
    for (int r = 0; r < 5; ++r) {
        int c = lane + r * 64;
        if (c < EMB) ag[c] = acc[r];
    }
}

// ---------------- weight transpose + split: W[K][Nc] -> Wt_{hi,lo}[Npad][Kpad] ----------------
__global__ __launch_bounds__(256) void wsplit_kernel(
    const float* __restrict__ W, int K, int Nc,
    ushort_t* __restrict__ hi, ushort_t* __restrict__ lo, int Kpad, int Npad)
{
    int idx = blockIdx.x * 256 + threadIdx.x;
    if (idx >= Npad * Kpad) return;
    int n = idx / Kpad, k = idx - n * Kpad;
    float v = (n < Nc && k < K) ? W[(size_t)k * Nc + n] : 0.f;
    ushort_t h = f2bf(v);
    hi[idx] = h;
    lo[idx] = f2bf(v - bf2f(h));
}

// ---------------- bf16x3 MFMA GEMM, fp32 A in (in-stage split), fp32 C out ----------------
// A[M,K] fp32 (lda arbitrary, 16B-aligned rows); B transposed hi/lo planes [Npad][Kpad].
// full_tile_out=1: write ALL tile rows, zero for gc>=Nvalid (K-pad prep for next GEMM).
__global__ __launch_bounds__(256) void gemm_mfma3_f32(
    const float* __restrict__ A, int lda, int Mvalid, int Kvalid,
    const ushort_t* __restrict__ Bhi, const ushort_t* __restrict__ Blo, int ldb,
    const float* __restrict__ bias, int Kpad, int Nvalid,
    float* __restrict__ C, int ldc, int relu, int full_tile_out)
{
    // LDS rows padded to 40 ushorts: frag ds_read_b128 slot = (5*row+c)%8 -> <=2-way (free)
    __shared__ ushort_t As[2][128][40];
    __shared__ ushort_t Bs[2][128][40];
    const int tid = threadIdx.x;
    const int lane = tid & 63, wid = tid >> 6;
    const int wr = wid >> 1, wc = wid & 1;          // 2x2 waves, 64x64 each
    const int lr = lane & 15, ko = (lane >> 4) * 8;
    const int row0 = blockIdx.y * 128, col0 = blockIdx.x * 128;
    const int srow = tid >> 1;           // staging row 0..127
    const int sc = (tid & 1) * 16;       // staging col base (16 elems per thread)

    const bool arow_ok = (row0 + srow) < Mvalid;
    const float* pA = A + (size_t)(row0 + srow) * lda + sc;
    const ushort_t* pBhi = Bhi + (size_t)(col0 + srow) * ldb + sc;
    const ushort_t* pBlo = Blo + (size_t)(col0 + srow) * ldb + sc;
    const f32x4 fz = {0.f, 0.f, 0.f, 0.f};

    f32x4 acc[4][4] = {};
    f32x4 LA[4];
    bf16x8 rB0, rB1, rB2, rB3;

    // prologue loads (k0 = 0)
    #pragma unroll
    for (int q = 0; q < 4; ++q) {
        int gk = sc + q * 4;
        LA[q] = (arow_ok && gk < Kvalid) ? *(const f32x4*)(pA + q * 4) : fz;
    }
    rB0 = *(const bf16x8*)(pBhi);     rB1 = *(const bf16x8*)(pBhi + 8);
    rB2 = *(const bf16x8*)(pBlo);     rB3 = *(const bf16x8*)(pBlo + 8);

    for (int k0 = 0; k0 < Kpad; k0 += 32) {
        // convert fp32 -> hi/lo bf16 in-register, then stage to LDS
        bf16x8 vh0, vh1, vl0, vl1;
        #pragma unroll
        for (int q = 0; q < 4; ++q) {
            #pragma unroll
            for (int j = 0; j < 4; ++j) {
                float v = LA[q][j];
                ushort_t H = f2bf(v);
                ushort_t Lo = f2bf(v - bf2f(H));
                if (q < 2) { vh0[q * 4 + j] = (short)H; vl0[q * 4 + j] = (short)Lo; }
                else       { vh1[(q - 2) * 4 + j] = (short)H; vl1[(q - 2) * 4 + j] = (short)Lo; }
            }
        }
        *(bf16x8*)&As[0][srow][sc]     = vh0;
        *(bf16x8*)&As[0][srow][sc + 8] = vh1;
        *(bf16x8*)&As[1][srow][sc]     = vl0;
        *(bf16x8*)&As[1][srow][sc + 8] = vl1;
        *(bf16x8*)&Bs[0][srow][sc]     = rB0;
        *(bf16x8*)&Bs[0][srow][sc + 8] = rB1;
        *(bf16x8*)&Bs[1][srow][sc]     = rB2;
        *(bf16x8*)&Bs[1][srow][sc + 8] = rB3;
        __syncthreads();
        if (k0 + 32 < Kpad) {   // issue next-tile global loads; latency hides under MFMAs
            int kn = k0 + 32;
            #pragma unroll
            for (int q = 0; q < 4; ++q) {
                int gk = kn + sc + q * 4;
                LA[q] = (arow_ok && gk < Kvalid) ? *(const f32x4*)(pA + kn + q * 4) : fz;
            }
            rB0 = *(const bf16x8*)(pBhi + kn);     rB1 = *(const bf16x8*)(pBhi + kn + 8);
            rB2 = *(const bf16x8*)(pBlo + kn);     rB3 = *(const bf16x8*)(pBlo + kn + 8);
        }
        bf16x8 afh[4], afl[4], bfh[4], bfl[4];
        #pragma unroll
        for (int f = 0; f < 4; ++f) {
            int ar = wr * 64 + f * 16 + lr;
            afh[f] = *(const bf16x8*)&As[0][ar][ko];
            afl[f] = *(const bf16x8*)&As[1][ar][ko];
            int bc = wc * 64 + f * 16 + lr;
            bfh[f] = *(const bf16x8*)&Bs[0][bc][ko];
            bfl[f] = *(const bf16x8*)&Bs[1][bc][ko];
        }
        #pragma unroll
        for (int f = 0; f < 4; ++f)
            #pragma unroll
            for (int g = 0; g < 4; ++g) {
                acc[f][g] = __builtin_amdgcn_mfma_f32_16x16x32_bf16(afh[f], bfh[g], acc[f][g], 0, 0, 0);
                acc[f][g] = __builtin_amdgcn_mfma_f32_16x16x32_bf16(afh[f], bfl[g], acc[f][g], 0, 0, 0);
                acc[f][g] = __builtin_amdgcn_mfma_f32_16x16x32_bf16(afl[f], bfh[g], acc[f][g], 0, 0, 0);
            }
        __syncthreads();
    }

    // epilogue: C/D mapping col=lane&15, row=(lane>>4)*4+reg  [m89-verified]
    #pragma unroll
    for (int f = 0; f < 4; ++f) {
        int grb = row0 + wr * 64 + f * 16 + (lane >> 4) * 4;
        #pragma unroll
        for (int g = 0; g < 4; ++g) {
            int gc = col0 + wc * 64 + g * 16 + lr;
            float bv = (gc < Nvalid) ? bias[gc] : 0.f;
            #pragma unroll
            for (int j = 0; j < 4; ++j) {
                int gr = grb + j;
                float v = acc[f][g][j] + bv;
                if (relu) v = fmaxf(v, 0.f);
                if (full_tile_out) {
                    if (gc >= Nvalid) v = 0.f;    // keep K-pad region zero for next GEMM
                    C[(size_t)gr * ldc + gc] = v;
                } else if (gr < Mvalid && gc < Nvalid) {
                    C[(size_t)gr * ldc + gc] = v;
                }
            }
        }
    }
}

// ---------------- fp32 GEMM (P-phase only) ----------------
#define TS 64
#define BKK 16
__global__ __launch_bounds__(256) void gemm_bias_act(
    const float* __restrict__ A, const float* __restrict__ W,
    const float* __restrict__ bias, float* __restrict__ C,
    int M, int K, int Nc, int relu_flag)
{
    __shared__ float Asm[BKK][TS + 4];
    __shared__ float Bsm[BKK][TS + 4];
    const int tid = threadIdx.x;
    const int tx = tid & 15, ty = tid >> 4;
    const int row0 = blockIdx.y * TS, col0 = blockIdx.x * TS;
    const int lka = tid & 15, lra = tid >> 4;
    const int lnb = tid & 63, lkb = tid >> 6;
    float acc[4][4] = {};
    for (int k0 = 0; k0 < K; k0 += BKK) {
        #pragma unroll
        for (int i = 0; i < 4; ++i) {
            int rr = lra + 16 * i;
            int gr = row0 + rr, gk = k0 + lka;
            Asm[lka][rr] = (gr < M && gk < K) ? A[(size_t)gr * K + gk] : 0.f;
        }
        #pragma unroll
        for (int i = 0; i < 4; ++i) {
            int kk = lkb + 4 * i;
            int gk = k0 + kk, gn = col0 + lnb;
            Bsm[kk][lnb] = (gk < K && gn < Nc) ? W[(size_t)gk * Nc + gn] : 0.f;
        }
        __syncthreads();
        #pragma unroll
        for (int kk = 0; kk < BKK; ++kk) {
            float a[4], b[4];
            #pragma unroll
            for (int i = 0; i < 4; ++i) a[i] = Asm[kk][ty * 4 + i];
            #pragma unroll
            for (int j = 0; j < 4; ++j) b[j] = Bsm[kk][tx * 4 + j];
            #pragma unroll
            for (int i = 0; i < 4; ++i)
                #pragma unroll
                for (int j = 0; j < 4; ++j)
                    acc[i][j] = fmaf(a[i], b[j], acc[i][j]);
        }
        __syncthreads();
    }
    #pragma unroll
    for (int i = 0; i < 4; ++i) {
        int gr = row0 + ty * 4 + i;
        if (gr >= M) continue;
        #pragma unroll
        for (int j = 0; j < 4; ++j) {
            int gn = col0 + tx * 4 + j;
            if (gn >= Nc) continue;
            float v = acc[i][j] + bias[gn];
            if (relu_flag) v = fmaxf(v, 0.f);
            C[(size_t)gr * Nc + gn] = v;
        }
    }
}

// ---------------- BN stats ----------------
__global__ __launch_bounds__(320) void bn_stats_kernel(
    const float* __restrict__ H, float* __restrict__ stats, int M, int rpb)
{
    int col = threadIdx.x;
    if (col >= EMB) return;
    int r0 = blockIdx.x * rpb;
    int r1 = min(M, r0 + rpb);
    float s = 0.f, s2 = 0.f;
    for (int r = r0; r < r1; ++r) {
        float v = H[(size_t)r * EMB + col];
        s += v;
        s2 = fmaf(v, v, s2);
    }
    atomicAdd(&stats[col], s);
    atomicAdd(&stats[EMB + col], s2);
}

// ---------------- BN apply ----------------
__global__ __launch_bounds__(256) void bn_apply_kernel(
    const float* __restrict__ h2, const float* __restrict__ stats,
    const float* __restrict__ g, const float* __restrict__ b,
    float* __restrict__ hout, int N, int relu_flag, float invN)
{
    int idx = blockIdx.x * blockDim.x + threadIdx.x;
    if (idx >= N * EMB) return;
    int col = idx % EMB;
    float mu = stats[col] * invN;
    float var = fmaf(-mu, mu, stats[EMB + col] * invN);
    float v = (h2[idx] - mu) * rsqrtf(var + 1e-5f) * g[col] + b[col];
    if (relu_flag) v = fmaxf(v, 0.f);
    hout[idx] = v;
}

// ---------------- fragment pool ----------------
__global__ __launch_bounds__(256) void pool_scatter_kernel(
    const float* __restrict__ h, const int* __restrict__ fb,
    float* __restrict__ pooled, float* __restrict__ cnt, int N)
{
    int wv = (blockIdx.x * blockDim.x + threadIdx.x) >> 6;
    int lane = threadIdx.x & 63;
    if (wv >= N) return;
    int p = fb[wv];
    const float* hr = h + (size_t)wv * EMB;
    float* pr = pooled + (size_t)p * EMB;
    for (int c = lane; c < EMB; c += 64) atomicAdd(&pr[c], hr[c]);
    if (lane == 0) atomicAdd(&cnt[p], 1.f);
}

__global__ __launch_bounds__(256) void pool_div_kernel(
    float* __restrict__ pooled, const float* __restrict__ cnt, int P)
{
    int idx = blockIdx.x * blockDim.x + threadIdx.x;
    if (idx >= P * EMB) return;
    pooled[idx] /= fmaxf(cnt[idx / EMB], 1.f);
}

// ---------------- row L2 normalize ----------------
__global__ __launch_bounds__(256) void normalize_rows_kernel(
    const float* __restrict__ X, float* __restrict__ Y, int M)
{
    int wv = (blockIdx.x * blockDim.x + threadIdx.x) >> 6;
    int lane = threadIdx.x & 63;
    if (wv >= M) return;
    const float* x = X + (size_t)wv * EMB;
    float ss = 0.f;
    for (int c = lane; c < EMB; c += 64) { float v = x[c]; ss = fmaf(v, v, ss); }
    #pragma unroll
    for (int o = 32; o > 0; o >>= 1) ss += __shfl_xor(ss, o, 64);
    float inv = 1.f / fmaxf(sqrtf(ss), 1e-12f);
    float* y = Y + (size_t)wv * EMB;
    for (int c = lane; c < EMB; c += 64) y[c] = x[c] * inv;
}

// ---------------- GCN ----------------
__global__ __launch_bounds__(256) void deg_kernel(
    const int* __restrict__ fei, float* __restrict__ deg, int FE)
{
    int i = blockIdx.x * blockDim.x + threadIdx.x;
    if (i < 2 * FE) atomicAdd(&deg[fei[i]], 1.f);
}

__global__ __launch_bounds__(256) void gcn_scatter_kernel(
    const float* __restrict__ xw, const int* __restrict__ fei,
    const int* __restrict__ dea, const float* __restrict__ e1,
    const float* __restrict__ e2, const float* __restrict__ deg,
    float* __restrict__ pred, int FE)
{
    int i = (blockIdx.x * blockDim.x + threadIdx.x) >> 6;
    int lane = threadIdx.x & 63;
    if (i >= 2 * FE) return;
    int u = fei[i];
    int v = (i < FE) ? fei[i + FE] : fei[i - FE];
    int er = (i < FE) ? i : i - FE;
    int a0 = dea[2 * er], a1 = dea[2 * er + 1];
    float du = deg[u], dv = deg[v];
    float su = du > 0.f ? rsqrtf(fmaxf(du, 1.f)) : 0.f;
    float sv = dv > 0.f ? rsqrtf(fmaxf(dv, 1.f)) : 0.f;
    float nr = su * sv;
    const float* xu = xw + (size_t)u * EMB;
    const float* t1 = e1 + (size_t)a0 * EMB;
    const float* t2 = e2 + (size_t)a1 * EMB;
    float* pv = pred + (size_t)v * EMB;
    for (int c = lane; c < EMB; c += 64)
        atomicAdd(&pv[c], nr * (xu[c] + t1[c] + t2[c]));
}

// ---------------- classifier ----------------
__global__ __launch_bounds__(256) void classifier_kernel(
    const float* __restrict__ f0, const float* __restrict__ f1,
    const float* __restrict__ w, const float* __restrict__ b,
    float* __restrict__ out, int P)
{
    int q = (blockIdx.x * blockDim.x + threadIdx.x) >> 6;
    int lane = threadIdx.x & 63;
    if (q >= 2 * P) return;
    int i = (q < P) ? q : q - P;
    int j = (q < P) ? i : (i == 0 ? P - 1 : i - 1);
    const float* a = f0 + (size_t)i * EMB;
    const float* c = f1 + (size_t)j * EMB;
    float s = 0.f;
    for (int k = lane; k < EMB; k += 64) s = fmaf(fmaxf(a[k], c[k]), w[k], s);
    #pragma unroll
    for (int o = 32; o > 0; o >>= 1) s += __shfl_xor(s, o, 64);
    if (lane == 0) out[q] = s + b[0];
}

extern "C" void kernel_launch(void* const* d_in, const int* in_sizes, int n_in,
                              void* d_out, int out_size, void* d_ws, size_t ws_size,
                              hipStream_t stream)
{
    const int*   x     = (const int*)d_in[0];
    const int*   ei    = (const int*)d_in[1];
    const int*   ea    = (const int*)d_in[2];
    const int*   fb    = (const int*)d_in[3];
    const int*   fei   = (const int*)d_in[4];
    const int*   dea   = (const int*)d_in[5];
    const float* atom1 = (const float*)d_in[7];
    const float* atom2 = (const float*)d_in[8];
    const float* ge1   = (const float*)d_in[9];
    const float* ge2   = (const float*)d_in[10];
    const float* w1    = (const float*)d_in[11];
    const float* b1    = (const float*)d_in[12];
    const float* w2    = (const float*)d_in[13];
    const float* b2    = (const float*)d_in[14];
    const float* bng   = (const float*)d_in[15];
    const float* bnb   = (const float*)d_in[16];
    const float* pw1   = (const float*)d_in[17];
    const float* pb1   = (const float*)d_in[18];
    const float* pw2   = (const float*)d_in[19];
    const float* pb2   = (const float*)d_in[20];
    const float* gw    = (const float*)d_in[21];
    const float* gb    = (const float*)d_in[22];
    const float* gcne1 = (const float*)d_in[23];
    const float* gcne2 = (const float*)d_in[24];
    const float* clw   = (const float*)d_in[25];
    const float* clb   = (const float*)d_in[26];
    (void)n_in;

    const int N  = in_sizes[0] / 2;
    const int E  = in_sizes[1] / 2;
    const int FE = in_sizes[4] / 2;
    const int P  = out_size / 2;
    float* outF = (float*)d_out;

    // ---- workspace carve ----
    char* wp = (char*)d_ws;
    size_t used = 0;
    auto carve = [&](size_t bytes) -> char* {
        char* r = wp;
        size_t a = (bytes + 255) & ~(size_t)255;
        wp += a;
        used += a;
        return r;
    };
    float* h     = (float*)carve((size_t)N * EMB * 4);   // 120 MB
    float* agg   = (float*)carve((size_t)N * EMB * 4);   // 120 MB; P-phase arena later
    float* stats = (float*)carve(2 * EMB * 4);
    float* cnt   = (float*)carve((size_t)P * 4);
    float* deg   = (float*)carve((size_t)P * 4);
    float* E12   = (float*)carve(18 * EMB * 4);
    // CSR (built once per call; edges layer-invariant)
    int* cnt_i   = (int*)carve((size_t)N * 4);
    int* csr_off = (int*)carve((size_t)(N + 1) * 4);
    int* cursor  = (int*)carve((size_t)N * 4);
    int* csr_eid = (int*)carve((size_t)E * 4);
    int* bsum    = (int*)carve(512 * 4);
    int* bbase   = (int*)carve(512 * 4);
    // split weights
    ushort_t* w1t_hi[NLAYER]; ushort_t* w1t_lo[NLAYER];
    ushort_t* w2t_hi[NLAYER]; ushort_t* w2t_lo[NLAYER];
    for (int l = 0; l < NLAYER; ++l) {
        w1t_hi[l] = (ushort_t*)carve((size_t)NP1 * KP1 * 2);
        w1t_lo[l] = (ushort_t*)carve((size_t)NP1 * KP1 * 2);
        w2t_hi[l] = (ushort_t*)carve((size_t)NP2 * NP1 * 2);
        w2t_lo[l] = (ushort_t*)carve((size_t)NP2 * NP1 * 2);
    }
    // adaptive chunk for fp32 hidden t [CH][NP1]
    size_t avail = (ws_size > used + (2u << 20)) ? (ws_size - used - (2u << 20)) : 0;
    long long chl = (long long)(avail / ((size_t)NP1 * 4));
    int Mfull_t = cdiv(N, 128) * 128;
    int CH = (int)((chl > Mfull_t) ? Mfull_t : chl);
    CH &= ~127;
    if (CH < 128) CH = 128;
    float* t = (float*)carve((size_t)CH * NP1 * 4);

    // P-phase buffers alias agg (dead after last bn_apply): 7 * P*EMB*4 = 84 MB <= 120 MB
    float* pooled = agg + 0 * (size_t)P * EMB;
    float* tmpP   = agg + 1 * (size_t)P * EMB;
    float* outp   = agg + 2 * (size_t)P * EMB;
    float* f0     = agg + 3 * (size_t)P * EMB;
    float* xw     = agg + 4 * (size_t)P * EMB;
    float* pred   = agg + 5 * (size_t)P * EMB;
    float* f1     = agg + 6 * (size_t)P * EMB;

    const int gElemsN = cdiv(N * EMB, 256);
    const int gElemsP = cdiv(P * EMB, 256);
    const int NB = cdiv(N, SCAN_B);   // 391 <= 512

    // ---- CSR build (once; dst = ei + E) ----
    izero_kernel<<<cdiv(N, 256), 256, 0, stream>>>(cnt_i, N);
    count_kernel<<<cdiv(E, 256), 256, 0, stream>>>(ei + E, cnt_i, E);
    scan_block_kernel<<<NB, SCAN_B, 0, stream>>>(cnt_i, csr_off, bsum, N);
    scan_partials_kernel<<<1, 512, 0, stream>>>(bsum, bbase, NB);
    scan_add_kernel<<<cdiv(N, 256), 256, 0, stream>>>(csr_off, bbase, N, E);
    izero_kernel<<<cdiv(N, 256), 256, 0, stream>>>(cursor, N);
    fill_kernel<<<cdiv(E, 256), 256, 0, stream>>>(ei + E, csr_off, cursor, csr_eid, E);

    // ---- split weights ----
    for (int l = 0; l < NLAYER; ++l) {
        wsplit_kernel<<<cdiv(NP1 * KP1, 256), 256, 0, stream>>>(
            w1 + (size_t)l * EMB * EMB2, EMB, EMB2, w1t_hi[l], w1t_lo[l], KP1, NP1);
        wsplit_kernel<<<cdiv(NP2 * NP1, 256), 256, 0, stream>>>(
            w2 + (size_t)l * EMB2 * EMB, EMB2, EMB, w2t_hi[l], w2t_lo[l], NP1, NP2);
    }

    // ---- embed ----
    embed_kernel<<<gElemsN, 256, 0, stream>>>(x, atom1, atom2, h, N);

    // ---- 5 GIN layers ----
    for (int l = 0; l < NLAYER; ++l) {
        e12_kernel<<<cdiv(18 * EMB, 256), 256, 0, stream>>>(
            ge1 + (size_t)l * 6 * EMB, ge2 + (size_t)l * 3 * EMB, E12);
        gin_gather_kernel<<<cdiv(N, 4), 256, 0, stream>>>(
            h, csr_off, csr_eid, ei, ea, E12, agg, N);
        for (int c0 = 0; c0 < N; c0 += CH) {
            int rows = min(CH, N - c0);
            int Mt = cdiv(rows, 128);
            gemm_mfma3_f32<<<dim3(NP1 / 128, Mt), 256, 0, stream>>>(
                agg + (size_t)c0 * EMB, EMB, rows, EMB,
                w1t_hi[l], w1t_lo[l], KP1,
                b1 + (size_t)l * EMB2, KP1, EMB2,
                t, NP1, 1, 1);
            gemm_mfma3_f32<<<dim3(NP2 / 128, Mt), 256, 0, stream>>>(
                t, NP1, rows, NP1,
                w2t_hi[l], w2t_lo[l], NP1,
                b2 + (size_t)l * EMB, NP1, EMB,
                agg + (size_t)c0 * EMB, EMB, 0, 0);
        }
        launch_zero(stats, 2 * EMB, stream);
        bn_stats_kernel<<<256, 320, 0, stream>>>(agg, stats, N, cdiv(N, 256));
        bn_apply_kernel<<<gElemsN, 256, 0, stream>>>(
            agg, stats, bng + (size_t)l * EMB, bnb + (size_t)l * EMB, h, N,
            (l < NLAYER - 1) ? 1 : 0, 1.f / (float)N);
    }

    // ---- fragment mean pool ----
    launch_zero(pooled, (size_t)P * EMB, stream);
    launch_zero(cnt, (size_t)P, stream);
    pool_scatter_kernel<<<cdiv(N, 4), 256, 0, stream>>>(h, fb, pooled, cnt, N);
    pool_div_kernel<<<gElemsP, 256, 0, stream>>>(pooled, cnt, P);

    // ---- projector MLP + normalize ----
    {
        dim3 g1(cdiv(EMB, TS), cdiv(P, TS));
        gemm_bias_act<<<g1, 256, 0, stream>>>(pooled, pw1, pb1, tmpP, P, EMB, EMB, 1);
        gemm_bias_act<<<g1, 256, 0, stream>>>(tmpP, pw2, pb2, outp, P, EMB, EMB, 0);
        normalize_rows_kernel<<<cdiv(P, 4), 256, 0, stream>>>(outp, f0, P);
    }

    // ---- GCN predictor ----
    {
        dim3 g1(cdiv(EMB, TS), cdiv(P, TS));
        gemm_bias_act<<<g1, 256, 0, stream>>>(outp, gw, gb, xw, P, EMB, EMB, 0);
        launch_zero(deg, (size_t)P, stream);
        launch_zero(pred, (size_t)P * EMB, stream);
        deg_kernel<<<cdiv(2 * FE, 256), 256, 0, stream>>>(fei, deg, FE);
        gcn_scatter_kernel<<<cdiv(2 * FE, 4), 256, 0, stream>>>(
            xw, fei, dea, gcne1, gcne2, deg, pred, FE);
        normalize_rows_kernel<<<cdiv(P, 4), 256, 0, stream>>>(pred, f1, P);
    }

    // ---- classifier ----
    classifier_kernel<<<cdiv(2 * P, 4), 256, 0, stream>>>(f0, f1, clw, clb, outF, P);
}

// Round 5
// 6850.887 us; speedup vs baseline: 1.8256x; 1.0581x over previous
//
#include <hip/hip_runtime.h>
#include <cstdint>
#include <cstddef>

#define EMB 300
#define EMB2 600
#define NLAYER 5
#define KP1 320     // padded K for GIN GEMM1 (300 -> 320)
#define NP1 640     // padded N for GEMM1 out / K for GEMM2 (600 -> 640)
#define NP2 384     // padded N-tile cover for GEMM2 out (300 -> 3*128)
#define SCAN_B 256

typedef short bf16x8 __attribute__((ext_vector_type(8)));
typedef float f32x4 __attribute__((ext_vector_type(4)));
typedef unsigned short ushort_t;

static inline int cdiv(int a, int b) { return (a + b - 1) / b; }

__device__ inline ushort_t f2bf(float v) {
    unsigned u = __float_as_uint(v);
    u += 0x7fffu + ((u >> 16) & 1u);
    return (ushort_t)(u >> 16);
}
__device__ inline float bf2f(ushort_t h) { return __uint_as_float(((unsigned)h) << 16); }

// BN+ReLU applied to 4 elems (affine per column)
__device__ inline f32x4 bnrelu4(f32x4 v, f32x4 s, f32x4 h, bool use_bn) {
    if (!use_bn) return v;
    f32x4 r;
    #pragma unroll
    for (int j = 0; j < 4; ++j) r[j] = fmaxf(fmaf(v[j], s[j], h[j]), 0.f);
    return r;
}

// ---------------- zero fill (capture-safe) ----------------
__global__ __launch_bounds__(256) void zero_kernel(float* __restrict__ p, size_t n)
{
    size_t i = (size_t)blockIdx.x * blockDim.x + threadIdx.x;
    size_t stride = (size_t)gridDim.x * blockDim.x;
    for (; i < n; i += stride) p[i] = 0.f;
}
static inline void launch_zero(float* p, size_t n, hipStream_t s)
{
    int g = (int)((n + 255) / 256);
    if (g > 2048) g = 2048;
    zero_kernel<<<g, 256, 0, s>>>(p, n);
}
__global__ __launch_bounds__(256) void izero_kernel(int* __restrict__ p, int n)
{
    int i = blockIdx.x * 256 + threadIdx.x;
    if (i < n) p[i] = 0;
}

// ---------------- embed ----------------
__global__ __launch_bounds__(256) void embed_kernel(
    const int* __restrict__ x, const float* __restrict__ a1,
    const float* __restrict__ a2, float* __restrict__ h, int N)
{
    int idx = blockIdx.x * blockDim.x + threadIdx.x;
    if (idx >= N * EMB) return;
    int row = idx / EMB, col = idx % EMB;
    h[idx] = a1[x[2 * row] * EMB + col] + a2[x[2 * row + 1] * EMB + col];
}

// ---------------- CSR build ----------------
__global__ __launch_bounds__(256) void count_kernel(
    const int* __restrict__ dst, int* __restrict__ cnt, int E)
{
    int e = blockIdx.x * 256 + threadIdx.x;
    if (e < E) atomicAdd(&cnt[dst[e]], 1);
}

__global__ __launch_bounds__(SCAN_B) void scan_block_kernel(
    const int* __restrict__ in, int* __restrict__ out, int* __restrict__ bsum, int n)
{
    __shared__ int s[SCAN_B];
    int t = threadIdx.x, i = blockIdx.x * SCAN_B + t;
    int v = (i < n) ? in[i] : 0;
    s[t] = v; __syncthreads();
    for (int o = 1; o < SCAN_B; o <<= 1) {
        int xv = (t >= o) ? s[t - o] : 0;
        __syncthreads();
        s[t] += xv;
        __syncthreads();
    }
    if (i < n) out[i] = s[t] - v;           // exclusive
    if (t == SCAN_B - 1) bsum[blockIdx.x] = s[t];
}

__global__ __launch_bounds__(512) void scan_partials_kernel(
    const int* __restrict__ bsum, int* __restrict__ bbase, int nb)
{
    __shared__ int s[512];
    int t = threadIdx.x;
    int v = (t < nb) ? bsum[t] : 0;
    s[t] = v; __syncthreads();
    for (int o = 1; o < 512; o <<= 1) {
        int xv = (t >= o) ? s[t - o] : 0;
        __syncthreads();
        s[t] += xv;
        __syncthreads();
    }
    if (t < nb) bbase[t] = s[t] - v;        // exclusive
}

__global__ __launch_bounds__(256) void scan_add_kernel(
    int* __restrict__ off, const int* __restrict__ bbase, int n, int total)
{
    int i = blockIdx.x * 256 + threadIdx.x;
    if (i < n) off[i] += bbase[i / SCAN_B];
    if (i == 0) off[n] = total;
}

__global__ __launch_bounds__(256) void fill_kernel(
    const int* __restrict__ dst, const int* __restrict__ off,
    int* __restrict__ cursor, int* __restrict__ eid, int E)
{
    int e = blockIdx.x * 256 + threadIdx.x;
    if (e >= E) return;
    int d = dst[e];
    int p = atomicAdd(&cursor[d], 1);
    eid[off[d] + p] = e;
}

// ---------------- fragment range offsets (frag_batch is SORTED) ----------------
__global__ __launch_bounds__(256) void poff_kernel(
    const int* __restrict__ fb, int* __restrict__ poff, int N, int P)
{
    int i = blockIdx.x * 256 + threadIdx.x;
    if (i >= N) return;
    int b = fb[i];
    if (i == 0) { for (int q = 0; q <= b; ++q) poff[q] = 0; }
    else { int a = fb[i - 1]; for (int q = a + 1; q <= b; ++q) poff[q] = i; }
    if (i == N - 1) { for (int q = b + 1; q <= P; ++q) poff[q] = N; }
}

// ---------------- all-layer edge-emb combo: E12all[l][a0*3+a1] ----------------
__global__ __launch_bounds__(256) void e12all_kernel(
    const float* __restrict__ ge1, const float* __restrict__ ge2,
    float* __restrict__ E12all)
{
    int idx = blockIdx.x * 256 + threadIdx.x;
    if (idx >= NLAYER * 18 * EMB) return;
    int l = idx / (18 * EMB);
    int rem = idx - l * 18 * EMB;
    int cmb = rem / EMB, c = rem - cmb * EMB;
    E12all[idx] = ge1[(size_t)l * 6 * EMB + (cmb / 3) * EMB + c]
                + ge2[(size_t)l * 3 * EMB + (cmb % 3) * EMB + c];
}

// ---------------- BN finalize: scale/shift per column ----------------
__global__ __launch_bounds__(256) void bn_finalize_kernel(
    const float* __restrict__ stats, const float* __restrict__ g,
    const float* __restrict__ b, float* __restrict__ scale,
    float* __restrict__ shift, float invN)
{
    int c = blockIdx.x * 256 + threadIdx.x;
    if (c >= EMB) return;
    float mu = stats[c] * invN;
    float var = fmaf(-mu, mu, stats[EMB + c] * invN);
    float s = rsqrtf(var + 1e-5f) * g[c];
    scale[c] = s;
    shift[c] = fmaf(-mu, s, b[c]);
}

// ---------------- GIN gather with inline BN+ReLU of previous layer ----------------
// agg[d] = f(hin[d]) + self + sum_in(f(hin[src]) + E12[cmb]),  f = bn+relu or id
__global__ __launch_bounds__(256) void gin_gather2(
    const float* __restrict__ hin, const float* __restrict__ scale,
    const float* __restrict__ shift, int use_bn,
    const int* __restrict__ off, const int* __restrict__ eid,
    const int* __restrict__ src, const int* __restrict__ ea,
    const float* __restrict__ E12, float* __restrict__ agg, int N)
{
    int node = (blockIdx.x * blockDim.x + threadIdx.x) >> 6;
    int lane = threadIdx.x & 63;
    if (node >= N) return;
    const bool tl = lane < 11;            // tail lanes cover cols 256..299
    const int c0 = lane * 4, c1 = 256 + lane * 4;
    f32x4 sc0 = {1,1,1,1}, sh0 = {0,0,0,0}, sc1 = {1,1,1,1}, sh1 = {0,0,0,0};
    if (use_bn) {
        sc0 = *(const f32x4*)(scale + c0); sh0 = *(const f32x4*)(shift + c0);
        if (tl) { sc1 = *(const f32x4*)(scale + c1); sh1 = *(const f32x4*)(shift + c1); }
    }
    const float* selfrow = E12 + 12 * EMB;   // (a0=4, a1=0)
    f32x4 a0, a1 = {0,0,0,0};
    {
        const float* hr = hin + (size_t)node * EMB;
        a0 = bnrelu4(*(const f32x4*)(hr + c0), sc0, sh0, use_bn) + *(const f32x4*)(selfrow + c0);
        if (tl) a1 = bnrelu4(*(const f32x4*)(hr + c1), sc1, sh1, use_bn) + *(const f32x4*)(selfrow + c1);
    }
    int j1 = off[node + 1];
    for (int j = off[node]; j < j1; ++j) {
        int e = eid[j];
        int s = src[e];
        int cmb = ea[2 * e] * 3 + ea[2 * e + 1];
        const float* hs = hin + (size_t)s * EMB;
        const float* er = E12 + (size_t)cmb * EMB;
        a0 += bnrelu4(*(const f32x4*)(hs + c0), sc0, sh0, use_bn) + *(const f32x4*)(er + c0);
        if (tl) a1 += bnrelu4(*(const f32x4*)(hs + c1), sc1, sh1, use_bn) + *(const f32x4*)(er + c1);
    }
    float* ag = agg + (size_t)node * EMB;
    *(f32x4*)(ag + c0) = a0;
    if (tl) *(f32x4*)(ag + c1) = a1;
}

// ---------------- fragment mean pool: contiguous ranges + analytic BN ----------------
// pooled[p] = (scale * sum(h2 rows) + cnt*shift) / max(cnt,1)   (no relu, last layer)
__global__ __launch_bounds__(256) void pool_gather_kernel(
    const float* __restrict__ hin, const float* __restrict__ scale,
    const float* __restrict__ shift, const int* __restrict__ poff,
    float* __restrict__ pooled, int P)
{
    int p = (blockIdx.x * blockDim.x + threadIdx.x) >> 6;
    int lane = threadIdx.x & 63;
    if (p >= P) return;
    const bool tl = lane < 11;
    const int c0 = lane * 4, c1 = 256 + lane * 4;
    int r0 = poff[p], r1 = poff[p + 1];
    f32x4 s0 = {0,0,0,0}, s1 = {0,0,0,0};
    for (int r = r0; r < r1; ++r) {
        const float* hr = hin + (size_t)r * EMB;
        s0 += *(const f32x4*)(hr + c0);
        if (tl) s1 += *(const f32x4*)(hr + c1);
    }
    float cntf = (float)(r1 - r0);
    float inv = 1.f / fmaxf(cntf, 1.f);
    f32x4 sc0 = *(const f32x4*)(scale + c0), sh0 = *(const f32x4*)(shift + c0);
    f32x4 o0;
    #pragma unroll
    for (int j = 0; j < 4; ++j) o0[j] = fmaf(s0[j], sc0[j], cntf * sh0[j]) * inv;
    float* pr = pooled + (size_t)p * EMB;
    *(f32x4*)(pr + c0) = o0;
    if (tl) {
        f32x4 sc1 = *(const f32x4*)(scale + c1), sh1 = *(const f32x4*)(shift + c1);
        f32x4 o1;
        #pragma unroll
        for (int j = 0; j < 4; ++j) o1[j] = fmaf(s1[j], sc1[j], cntf * sh1[j]) * inv;
        *(f32x4*)(pr + c1) = o1;
    }
}

// ---------------- weight transpose + split ----------------
__global__ __launch_bounds__(256) void wsplit_kernel(
    const float* __restrict__ W, int K, int Nc,
    ushort_t* __restrict__ hi, ushort_t* __restrict__ lo, int Kpad, int Npad)
{
    int idx = blockIdx.x * 256 + threadIdx.x;
    if (idx >= Npad * Kpad) return;
    int n = idx / Kpad, k = idx - n * Kpad;
    float v = (n < Nc && k < K) ? W[(size_t)k * Nc + n] : 0.f;
    ushort_t h = f2bf(v);
    hi[idx] = h;
    lo[idx] = f2bf(v - bf2f(h));
}

// ---------------- bf16x3 MFMA GEMM (fp32 A, in-stage split; optional BN-stats epilogue) ----------------
__global__ __launch_bounds__(256) void gemm_mfma3_f32(
    const float* __restrict__ A, int lda, int Mvalid, int Kvalid,
    const ushort_t* __restrict__ Bhi, const ushort_t* __restrict__ Blo, int ldb,
    const float* __restrict__ bias, int Kpad, int Nvalid,
    float* __restrict__ C, int ldc, int relu, int full_tile_out,
    float* __restrict__ stats)
{
    __shared__ ushort_t As[2][128][40];
    __shared__ ushort_t Bs[2][128][40];
    __shared__ float cred[128][2];
    const int tid = threadIdx.x;
    const int lane = tid & 63, wid = tid >> 6;
    const int wr = wid >> 1, wc = wid & 1;
    const int lr = lane & 15, ko = (lane >> 4) * 8;

    // bijective XCD swizzle (m204) on flattened block id, x-major decompose
    int gx = gridDim.x;
    int nwg = gx * gridDim.y;
    int flat = blockIdx.y * gx + blockIdx.x;
    if (nwg >= 8) {
        int q = nwg >> 3, r = nwg & 7, xc = flat & 7, s = flat >> 3;
        flat = (xc < r ? xc * (q + 1) : r * (q + 1) + (xc - r) * q) + s;
    }
    const int row0 = (flat / gx) * 128, col0 = (flat % gx) * 128;

    const int srow = tid >> 1;
    const int sc = (tid & 1) * 16;

    const bool arow_ok = (row0 + srow) < Mvalid;
    const float* pA = A + (size_t)(row0 + srow) * lda + sc;
    const ushort_t* pBhi = Bhi + (size_t)(col0 + srow) * ldb + sc;
    const ushort_t* pBlo = Blo + (size_t)(col0 + srow) * ldb + sc;
    const f32x4 fz = {0.f, 0.f, 0.f, 0.f};

    f32x4 acc[4][4] = {};
    f32x4 LA[4];
    bf16x8 rB0, rB1, rB2, rB3;

    #pragma unroll
    for (int q = 0; q < 4; ++q) {
        int gk = sc + q * 4;
        LA[q] = (arow_ok && gk < Kvalid) ? *(const f32x4*)(pA + q * 4) : fz;
    }
    rB0 = *(const bf16x8*)(pBhi);     rB1 = *(const bf16x8*)(pBhi + 8);
    rB2 = *(const bf16x8*)(pBlo);     rB3 = *(const bf16x8*)(pBlo + 8);

    for (int k0 = 0; k0 < Kpad; k0 += 32) {
        bf16x8 vh0, vh1, vl0, vl1;
        #pragma unroll
        for (int q = 0; q < 4; ++q) {
            #pragma unroll
            for (int j = 0; j < 4; ++j) {
                float v = LA[q][j];
                ushort_t H = f2bf(v);
                ushort_t Lo = f2bf(v - bf2f(H));
                if (q < 2) { vh0[q * 4 + j] = (short)H; vl0[q * 4 + j] = (short)Lo; }
                else       { vh1[(q - 2) * 4 + j] = (short)H; vl1[(q - 2) * 4 + j] = (short)Lo; }
            }
        }
        *(bf16x8*)&As[0][srow][sc]     = vh0;
        *(bf16x8*)&As[0][srow][sc + 8] = vh1;
        *(bf16x8*)&As[1][srow][sc]     = vl0;
        *(bf16x8*)&As[1][srow][sc + 8] = vl1;
        *(bf16x8*)&Bs[0][srow][sc]     = rB0;
        *(bf16x8*)&Bs[0][srow][sc + 8] = rB1;
        *(bf16x8*)&Bs[1][srow][sc]     = rB2;
        *(bf16x8*)&Bs[1][srow][sc + 8] = rB3;
        __syncthreads();
        if (k0 + 32 < Kpad) {
            int kn = k0 + 32;
            #pragma unroll
            for (int q = 0; q < 4; ++q) {
                int gk = kn + sc + q * 4;
                LA[q] = (arow_ok && gk < Kvalid) ? *(const f32x4*)(pA + kn + q * 4) : fz;
            }
            rB0 = *(const bf16x8*)(pBhi + kn);     rB1 = *(const bf16x8*)(pBhi + kn + 8);
            rB2 = *(const bf16x8*)(pBlo + kn);     rB3 = *(const bf16x8*)(pBlo + kn + 8);
        }
        bf16x8 afh[4], afl[4], bfh[4], bfl[4];
        #pragma unroll
        for (int f = 0; f < 4; ++f) {
            int ar = wr * 64 + f * 16 + lr;
            afh[f] = *(const bf16x8*)&As[0][ar][ko];
            afl[f] = *(const bf16x8*)&As[1][ar][ko];
            int bc = wc * 64 + f * 16 + lr;
            bfh[f] = *(const bf16x8*)&Bs[0][bc][ko];
            bfl[f] = *(const bf16x8*)&Bs[1][bc][ko];
        }
        #pragma unroll
        for (int f = 0; f < 4; ++f)
            #pragma unroll
            for (int g = 0; g < 4; ++g) {
                acc[f][g] = __builtin_amdgcn_mfma_f32_16x16x32_bf16(afh[f], bfh[g], acc[f][g], 0, 0, 0);
                acc[f][g] = __builtin_amdgcn_mfma_f32_16x16x32_bf16(afh[f], bfl[g], acc[f][g], 0, 0, 0);
                acc[f][g] = __builtin_amdgcn_mfma_f32_16x16x32_bf16(afl[f], bfh[g], acc[f][g], 0, 0, 0);
            }
        __syncthreads();
    }

    // epilogue: C/D mapping col=lane&15, row=(lane>>4)*4+reg  [m89-verified]
    float ts[4] = {0.f, 0.f, 0.f, 0.f}, ts2[4] = {0.f, 0.f, 0.f, 0.f};
    #pragma unroll
    for (int f = 0; f < 4; ++f) {
        int grb = row0 + wr * 64 + f * 16 + (lane >> 4) * 4;
        #pragma unroll
        for (int g = 0; g < 4; ++g) {
            int gc = col0 + wc * 64 + g * 16 + lr;
            float bv = (gc < Nvalid) ? bias[gc] : 0.f;
            #pragma unroll
            for (int j = 0; j < 4; ++j) {
                int gr = grb + j;
                float v = acc[f][g][j] + bv;
                if (relu) v = fmaxf(v, 0.f);
                if (full_tile_out) {
                    if (gc >= Nvalid) v = 0.f;
                    C[(size_t)gr * ldc + gc] = v;
                } else if (gr < Mvalid && gc < Nvalid) {
                    C[(size_t)gr * ldc + gc] = v;
                    ts[g] += v;
                    ts2[g] = fmaf(v, v, ts2[g]);
                }
            }
        }
    }
    if (stats) {
        ((float*)cred)[tid] = 0.f;       // 256 slots
        __syncthreads();
        #pragma unroll
        for (int g = 0; g < 4; ++g) {
            int cidx = wc * 64 + g * 16 + lr;
            atomicAdd(&cred[cidx][0], ts[g]);
            atomicAdd(&cred[cidx][1], ts2[g]);
        }
        __syncthreads();
        if (tid < 128) {
            int gc = col0 + tid;
            if (gc < Nvalid) {
                atomicAdd(&stats[gc], cred[tid][0]);
                atomicAdd(&stats[EMB + gc], cred[tid][1]);
            }
        }
    }
}

// ---------------- fp32 GEMM (P-phase only) ----------------
#define TS 64
#define BKK 16
__global__ __launch_bounds__(256) void gemm_bias_act(
    const float* __restrict__ A, const float* __restrict__ W,
    const float* __restrict__ bias, float* __restrict__ C,
    int M, int K, int Nc, int relu_flag)
{
    __shared__ float Asm[BKK][TS + 4];
    __shared__ float Bsm[BKK][TS + 4];
    const int tid = threadIdx.x;
    const int tx = tid & 15, ty = tid >> 4;
    const int row0 = blockIdx.y * TS, col0 = blockIdx.x * TS;
    const int lka = tid & 15, lra = tid >> 4;
    const int lnb = tid & 63, lkb = tid >> 6;
    float acc[4][4] = {};
    for (int k0 = 0; k0 < K; k0 += BKK) {
        #pragma unroll
        for (int i = 0; i < 4; ++i) {
            int rr = lra + 16 * i;
            int gr = row0 + rr, gk = k0 + lka;
            Asm[lka][rr] = (gr < M && gk < K) ? A[(size_t)gr * K + gk] : 0.f;
        }
        #pragma unroll
        for (int i = 0; i < 4; ++i) {
            int kk = lkb + 4 * i;
            int gk = k0 + kk, gn = col0 + lnb;
            Bsm[kk][lnb] = (gk < K && gn < Nc) ? W[(size_t)gk * Nc + gn] : 0.f;
        }
        __syncthreads();
        #pragma unroll
        for (int kk = 0; kk < BKK; ++kk) {
            float a[4], b[4];
            #pragma unroll
            for (int i = 0; i < 4; ++i) a[i] = Asm[kk][ty * 4 + i];
            #pragma unroll
            for (int j = 0; j < 4; ++j) b[j] = Bsm[kk][tx * 4 + j];
            #pragma unroll
            for (int i = 0; i < 4; ++i)
                #pragma unroll
                for (int j = 0; j < 4; ++j)
                    acc[i][j] = fmaf(a[i], b[j], acc[i][j]);
        }
        __syncthreads();
    }
    #pragma unroll
    for (int i = 0; i < 4; ++i) {
        int gr = row0 + ty * 4 + i;
        if (gr >= M) continue;
        #pragma unroll
        for (int j = 0; j < 4; ++j) {
            int gn = col0 + tx * 4 + j;
            if (gn >= Nc) continue;
            float v = acc[i][j] + bias[gn];
            if (relu_flag) v = fmaxf(v, 0.f);
            C[(size_t)gr * Nc + gn] = v;
        }
    }
}

// ---------------- row L2 normalize ----------------
__global__ __launch_bounds__(256) void normalize_rows_kernel(
    const float* __restrict__ X, float* __restrict__ Y, int M)
{
    int wv = (blockIdx.x * blockDim.x + threadIdx.x) >> 6;
    int lane = threadIdx.x & 63;
    if (wv >= M) return;
    const float* x = X + (size_t)wv * EMB;
    float ss = 0.f;
    for (int c = lane; c < EMB; c += 64) { float v = x[c]; ss = fmaf(v, v, ss); }
    #pragma unroll
    for (int o = 32; o > 0; o >>= 1) ss += __shfl_xor(ss, o, 64);
    float inv = 1.f / fmaxf(sqrtf(ss), 1e-12f);
    float* y = Y + (size_t)wv * EMB;
    for (int c = lane; c < EMB; c += 64) y[c] = x[c] * inv;
}

// ---------------- GCN ----------------
__global__ __launch_bounds__(256) void deg_kernel(
    const int* __restrict__ fei, float* __restrict__ deg, int FE)
{
    int i = blockIdx.x * blockDim.x + threadIdx.x;
    if (i < 2 * FE) atomicAdd(&deg[fei[i]], 1.f);
}

__global__ __launch_bounds__(256) void gcn_scatter_kernel(
    const float* __restrict__ xw, const int* __restrict__ fei,
    const int* __restrict__ dea, const float* __restrict__ e1,
    const float* __restrict__ e2, const float* __restrict__ deg,
    float* __restrict__ pred, int FE)
{
    int i = (blockIdx.x * blockDim.x + threadIdx.x) >> 6;
    int lane = threadIdx.x & 63;
    if (i >= 2 * FE) return;
    int u = fei[i];
    int v = (i < FE) ? fei[i + FE] : fei[i - FE];
    int er = (i < FE) ? i : i - FE;
    int a0 = dea[2 * er], a1 = dea[2 * er + 1];
    float du = deg[u], dv = deg[v];
    float su = du > 0.f ? rsqrtf(fmaxf(du, 1.f)) : 0.f;
    float sv = dv > 0.f ? rsqrtf(fmaxf(dv, 1.f)) : 0.f;
    float nr = su * sv;
    const float* xu = xw + (size_t)u * EMB;
    const float* t1 = e1 + (size_t)a0 * EMB;
    const float* t2 = e2 + (size_t)a1 * EMB;
    float* pv = pred + (size_t)v * EMB;
    for (int c = lane; c < EMB; c += 64)
        atomicAdd(&pv[c], nr * (xu[c] + t1[c] + t2[c]));
}

// ---------------- classifier ----------------
__global__ __launch_bounds__(256) void classifier_kernel(
    const float* __restrict__ f0, const float* __restrict__ f1,
    const float* __restrict__ w, const float* __restrict__ b,
    float* __restrict__ out, int P)
{
    int q = (blockIdx.x * blockDim.x + threadIdx.x) >> 6;
    int lane = threadIdx.x & 63;
    if (q >= 2 * P) return;
    int i = (q < P) ? q : q - P;
    int j = (q < P) ? i : (i == 0 ? P - 1 : i - 1);
    const float* a = f0 + (size_t)i * EMB;
    const float* c = f1 + (size_t)j * EMB;
    float s = 0.f;
    for (int k = lane; k < EMB; k += 64) s = fmaf(fmaxf(a[k], c[k]), w[k], s);
    #pragma unroll
    for (int o = 32; o > 0; o >>= 1) s += __shfl_xor(s, o, 64);
    if (lane == 0) out[q] = s + b[0];
}

extern "C" void kernel_launch(void* const* d_in, const int* in_sizes, int n_in,
                              void* d_out, int out_size, void* d_ws, size_t ws_size,
                              hipStream_t stream)
{
    const int*   x     = (const int*)d_in[0];
    const int*   ei    = (const int*)d_in[1];
    const int*   ea    = (const int*)d_in[2];
    const int*   fb    = (const int*)d_in[3];
    const int*   fei   = (const int*)d_in[4];
    const int*   dea   = (const int*)d_in[5];
    const float* atom1 = (const float*)d_in[7];
    const float* atom2 = (const float*)d_in[8];
    const float* ge1   = (const float*)d_in[9];
    const float* ge2   = (const float*)d_in[10];
    const float* w1    = (const float*)d_in[11];
    const float* b1    = (const float*)d_in[12];
    const float* w2    = (const float*)d_in[13];
    const float* b2    = (const float*)d_in[14];
    const float* bng   = (const float*)d_in[15];
    const float* bnb   = (const float*)d_in[16];
    const float* pw1   = (const float*)d_in[17];
    const float* pb1   = (const float*)d_in[18];
    const float* pw2   = (const float*)d_in[19];
    const float* pb2   = (const float*)d_in[20];
    const float* gw    = (const float*)d_in[21];
    const float* gb    = (const float*)d_in[22];
    const float* gcne1 = (const float*)d_in[23];
    const float* gcne2 = (const float*)d_in[24];
    const float* clw   = (const float*)d_in[25];
    const float* clb   = (const float*)d_in[26];
    (void)n_in;

    const int N  = in_sizes[0] / 2;
    const int E  = in_sizes[1] / 2;
    const int FE = in_sizes[4] / 2;
    const int P  = out_size / 2;
    float* outF = (float*)d_out;

    // ---- workspace carve ----
    char* wp = (char*)d_ws;
    size_t used = 0;
    auto carve = [&](size_t bytes) -> char* {
        char* r = wp;
        size_t a = (bytes + 255) & ~(size_t)255;
        wp += a;
        used += a;
        return r;
    };
    float* X = (float*)carve((size_t)N * EMB * 4);   // embed out / h2 storage (120 MB)
    float* Y = (float*)carve((size_t)N * EMB * 4);   // agg; later P-phase arena (120 MB)
    float* statsAll = (float*)carve((size_t)NLAYER * 2 * EMB * 4);
    float* scaleAll = (float*)carve((size_t)NLAYER * EMB * 4);
    float* shiftAll = (float*)carve((size_t)NLAYER * EMB * 4);
    float* E12all   = (float*)carve((size_t)NLAYER * 18 * EMB * 4);
    float* deg      = (float*)carve((size_t)P * 4);
    int* poff    = (int*)carve((size_t)(P + 1) * 4);
    int* cnt_i   = (int*)carve((size_t)N * 4);
    int* csr_off = (int*)carve((size_t)(N + 1) * 4);
    int* cursor  = (int*)carve((size_t)N * 4);
    int* csr_eid = (int*)carve((size_t)E * 4);
    int* bsum    = (int*)carve(512 * 4);
    int* bbase   = (int*)carve(512 * 4);
    ushort_t* w1t_hi[NLAYER]; ushort_t* w1t_lo[NLAYER];
    ushort_t* w2t_hi[NLAYER]; ushort_t* w2t_lo[NLAYER];
    for (int l = 0; l < NLAYER; ++l) {
        w1t_hi[l] = (ushort_t*)carve((size_t)NP1 * KP1 * 2);
        w1t_lo[l] = (ushort_t*)carve((size_t)NP1 * KP1 * 2);
        w2t_hi[l] = (ushort_t*)carve((size_t)NP2 * NP1 * 2);
        w2t_lo[l] = (ushort_t*)carve((size_t)NP2 * NP1 * 2);
    }
    size_t avail = (ws_size > used + (2u << 20)) ? (ws_size - used - (2u << 20)) : 0;
    long long chl = (long long)(avail / ((size_t)NP1 * 4));
    int Mfull_t = cdiv(N, 128) * 128;
    int CH = (int)((chl > Mfull_t) ? Mfull_t : chl);
    CH &= ~127;
    if (CH < 128) CH = 128;
    float* t = (float*)carve((size_t)CH * NP1 * 4);

    // P-phase buffers alias Y (dead after pool): 7 * P*EMB*4 = 84 MB <= 120 MB
    float* pooled = Y + 0 * (size_t)P * EMB;
    float* tmpP   = Y + 1 * (size_t)P * EMB;
    float* outp   = Y + 2 * (size_t)P * EMB;
    float* f0     = Y + 3 * (size_t)P * EMB;
    float* xw     = Y + 4 * (size_t)P * EMB;
    float* pred   = Y + 5 * (size_t)P * EMB;
    float* f1     = Y + 6 * (size_t)P * EMB;

    const int gElemsN = cdiv(N * EMB, 256);
    const int NB = cdiv(N, SCAN_B);

    // ---- one-time per call: CSR, poff, E12, weight split, stats zero ----
    izero_kernel<<<cdiv(N, 256), 256, 0, stream>>>(cnt_i, N);
    count_kernel<<<cdiv(E, 256), 256, 0, stream>>>(ei + E, cnt_i, E);
    scan_block_kernel<<<NB, SCAN_B, 0, stream>>>(cnt_i, csr_off, bsum, N);
    scan_partials_kernel<<<1, 512, 0, stream>>>(bsum, bbase, NB);
    scan_add_kernel<<<cdiv(N, 256), 256, 0, stream>>>(csr_off, bbase, N, E);
    izero_kernel<<<cdiv(N, 256), 256, 0, stream>>>(cursor, N);
    fill_kernel<<<cdiv(E, 256), 256, 0, stream>>>(ei + E, csr_off, cursor, csr_eid, E);
    poff_kernel<<<cdiv(N, 256), 256, 0, stream>>>(fb, poff, N, P);
    e12all_kernel<<<cdiv(NLAYER * 18 * EMB, 256), 256, 0, stream>>>(ge1, ge2, E12all);
    for (int l = 0; l < NLAYER; ++l) {
        wsplit_kernel<<<cdiv(NP1 * KP1, 256), 256, 0, stream>>>(
            w1 + (size_t)l * EMB * EMB2, EMB, EMB2, w1t_hi[l], w1t_lo[l], KP1, NP1);
        wsplit_kernel<<<cdiv(NP2 * NP1, 256), 256, 0, stream>>>(
            w2 + (size_t)l * EMB2 * EMB, EMB2, EMB, w2t_hi[l], w2t_lo[l], NP1, NP2);
    }
    launch_zero(statsAll, (size_t)NLAYER * 2 * EMB, stream);

    // ---- embed ----
    embed_kernel<<<gElemsN, 256, 0, stream>>>(x, atom1, atom2, X, N);

    // ---- 5 GIN layers: gather(BN_{l-1} inline) -> gemm1 -> gemm2(+stats_l) -> finalize_l ----
    for (int l = 0; l < NLAYER; ++l) {
        gin_gather2<<<cdiv(N, 4), 256, 0, stream>>>(
            X, scaleAll + (size_t)(l > 0 ? l - 1 : 0) * EMB,
            shiftAll + (size_t)(l > 0 ? l - 1 : 0) * EMB, (l > 0) ? 1 : 0,
            csr_off, csr_eid, ei, ea, E12all + (size_t)l * 18 * EMB, Y, N);
        for (int c0 = 0; c0 < N; c0 += CH) {
            int rows = min(CH, N - c0);
            int Mt = cdiv(rows, 128);
            gemm_mfma3_f32<<<dim3(NP1 / 128, Mt), 256, 0, stream>>>(
                Y + (size_t)c0 * EMB, EMB, rows, EMB,
                w1t_hi[l], w1t_lo[l], KP1,
                b1 + (size_t)l * EMB2, KP1, EMB2,
                t, NP1, 1, 1, nullptr);
            gemm_mfma3_f32<<<dim3(NP2 / 128, Mt), 256, 0, stream>>>(
                t, NP1, rows, NP1,
                w2t_hi[l], w2t_lo[l], NP1,
                b2 + (size_t)l * EMB, NP1, EMB,
                X + (size_t)c0 * EMB, EMB, 0, 0, statsAll + (size_t)l * 2 * EMB);
        }
        bn_finalize_kernel<<<cdiv(EMB, 256), 256, 0, stream>>>(
            statsAll + (size_t)l * 2 * EMB, bng + (size_t)l * EMB, bnb + (size_t)l * EMB,
            scaleAll + (size_t)l * EMB, shiftAll + (size_t)l * EMB, 1.f / (float)N);
    }

    // ---- fragment mean pool (BN of last layer applied analytically) ----
    pool_gather_kernel<<<cdiv(P, 4), 256, 0, stream>>>(
        X, scaleAll + (size_t)(NLAYER - 1) * EMB, shiftAll + (size_t)(NLAYER - 1) * EMB,
        poff, pooled, P);

    // ---- projector MLP + normalize ----
    {
        dim3 g1(cdiv(EMB, TS), cdiv(P, TS));
        gemm_bias_act<<<g1, 256, 0, stream>>>(pooled, pw1, pb1, tmpP, P, EMB, EMB, 1);
        gemm_bias_act<<<g1, 256, 0, stream>>>(tmpP, pw2, pb2, outp, P, EMB, EMB, 0);
        normalize_rows_kernel<<<cdiv(P, 4), 256, 0, stream>>>(outp, f0, P);
    }

    // ---- GCN predictor ----
    {
        dim3 g1(cdiv(EMB, TS), cdiv(P, TS));
        gemm_bias_act<<<g1, 256, 0, stream>>>(outp, gw, gb, xw, P, EMB, EMB, 0);
        launch_zero(deg, (size_t)P, stream);
        launch_zero(pred, (size_t)P * EMB, stream);
        deg_kernel<<<cdiv(2 * FE, 256), 256, 0, stream>>>(fei, deg, FE);
        gcn_scatter_kernel<<<cdiv(2 * FE, 4), 256, 0, stream>>>(
            xw, fei, dea, gcne1, gcne2, deg, pred, FE);
        normalize_rows_kernel<<<cdiv(P, 4), 256, 0, stream>>>(pred, f1, P);
    }

    // ---- classifier ----
    classifier_kernel<<<cdiv(2 * P, 4), 256, 0, stream>>>(f0, f1, clw, clb, outF, P);
}